// Round 1
// 121.115 us; speedup vs baseline: 1.0344x; 1.0344x over previous
//
#include <hip/hip_runtime.h>
#include <math.h>

#define TPB 256
#define TPBS 1024    // select block size
#define LDSF 12288   // select LDS stage capacity in floats (48 KB)
#define HP 17        // hist stride: 16 waves + 1 pad (same bin spans 16 banks)

typedef unsigned long long ull;
typedef float pf4 __attribute__((ext_vector_type(4), aligned(4)));  // 4B-aligned float4

__device__ __forceinline__ float jac(float tx0, float ty0, float tx1, float ty1, float ta,
                                     float px0, float py0, float px1, float py1, float pa) {
    float ltx = fmaxf(tx0, px0), lty = fmaxf(ty0, py0);
    float rbx = fminf(tx1, px1), rby = fminf(ty1, py1);
    float w = fmaxf(rbx - ltx, 0.0f), h = fmaxf(rby - lty, 0.0f);
    float inter = w * h;
    return inter / (ta + pa - inter);
}

// ONE pass over all priors (grid B*CB2, thread-per-prior), producing:
//  - per-chunk per-o best-prior key partials (jac computed ONCE for both the
//    per-o argmax and the per-p sweep)
//  - TENTATIVE mined / smooth-L1 / positive sums (no forced-match override —
//    fixed up in select; proven bit-exact in R9/R11)
// Per-o argmax: f32 wave max-reduce + ballot; lowest lane with ov==mx gives
// the smallest p (reference first-max tiebreak). Cross-chunk key stays
// (ov_bits<<32) | (0xFFFFFFFF - p): ov >= 0 -> bit-monotone.
template <int ON, int CN>
__global__ __launch_bounds__(TPB) void fused_kernel(
    const float* __restrict__ loc, const float* __restrict__ priors,
    const float* __restrict__ targets, const float* __restrict__ conf,
    int P, int O_rt, int C_rt, int CB2,
    float* __restrict__ mined, ull* __restrict__ pkeys,
    float* __restrict__ part_ll, float* __restrict__ part_pc,
    int* __restrict__ part_np) {
    constexpr int OMAX = (ON > 0) ? ON : 64;
    constexpr int CC = (CN > 0) ? CN : 32;
    const int O = (ON > 0) ? ON : O_rt;
    const int C = (CN > 0) ? CN : C_rt;
    const int b = blockIdx.x / CB2;
    const int chunk = blockIdx.x % CB2;
    const int tid = threadIdx.x;
    const int p = chunk * TPB + tid;
    const bool pv = (p < P);
    const int lane = tid & 63, wv = tid >> 6;

    __shared__ float s_tx0[OMAX], s_ty0[OMAX], s_tx1[OMAX], s_ty1[OMAX];
    __shared__ float s_lab[OMAX], s_area[OMAX];
    __shared__ ull s_wk[TPB / 64][OMAX];
    __shared__ float s_wll[TPB / 64], s_wpc[TPB / 64];
    __shared__ int s_wnp[TPB / 64];

    // ---- issue conf-row + prior loads FIRST (latency overlaps setup) ----
    float rv[CC];
    float4 pr4 = make_float4(0.f, 0.f, 1.f, 1.f);
    if (pv) {
        const float* row = conf + ((size_t)b * P + p) * C;
        if (CN > 0) {
#pragma unroll
            for (int q = 0; q < CN / 4; ++q) {
                pf4 v = *(const pf4*)(row + 4 * q);
#pragma unroll
                for (int e = 0; e < 4; ++e) rv[4 * q + e] = v[e];
            }
#pragma unroll
            for (int j = (CN / 4) * 4; j < CN; ++j) rv[j] = row[j];
        } else {
            for (int j = 0; j < C; ++j) rv[j] = row[j];
        }
        pr4 = ((const float4*)priors)[p];
    }

    for (int o = tid; o < O; o += TPB) {
        const float* t = targets + ((size_t)b * O + o) * 5;
        float x0 = t[0], y0 = t[1], x1 = t[2], y1 = t[3];
        s_tx0[o] = x0; s_ty0[o] = y0; s_tx1[o] = x1; s_ty1[o] = y1;
        s_lab[o] = t[4];
        s_area[o] = (x1 - x0) * (y1 - y0);
    }
    __syncthreads();

    // ---- jac sweep: tentative per-p best (first-max over o) AND per-o
    //      wave argmax via f32 max-reduce + ballot (cheap; exact tiebreak) ----
    float cx = pr4.x, cy = pr4.y, pw = pr4.z, ph = pr4.w;
    float px0 = cx - pw * 0.5f, py0 = cy - ph * 0.5f;
    float px1 = cx + pw * 0.5f, py1 = cy + ph * 0.5f;
    float pa = (px1 - px0) * (py1 - py0);
    float bto = -1.0f;
    int bti = 0;
    for (int o = 0; o < O; ++o) {
        float ov = -1.0f;  // invalid lanes never win (mx >= 0 when any valid)
        if (pv) {
            ov = jac(s_tx0[o], s_ty0[o], s_tx1[o], s_ty1[o], s_area[o],
                     px0, py0, px1, py1, pa);
            if (ov > bto) { bto = ov; bti = o; }  // strictly > keeps earliest o
        }
        float mx = ov;
#pragma unroll
        for (int d = 1; d < 64; d <<= 1)
            mx = fmaxf(mx, __shfl_xor(mx, d, 64));
        ull kk = 0ull;
        if (mx >= 0.0f) {  // wave has at least one valid lane
            ull msk = __ballot(ov == mx);
            int src = __ffsll(msk) - 1;  // lowest lane = smallest p on ties
            unsigned pw_ = (unsigned)(chunk * TPB + (wv << 6) + src);
            kk = ((ull)__float_as_uint(mx) << 32) | (ull)(0xFFFFFFFFu - pw_);
        }
        if (lane == 0) s_wk[wv][o] = kk;
    }
    __syncthreads();
    if (tid < O) {
        ull kk = s_wk[0][tid];
        for (int w = 1; w < TPB / 64; ++w)
            if (s_wk[w][tid] > kk) kk = s_wk[w][tid];
        pkeys[((size_t)b * O + tid) * CB2 + chunk] = kk;
    }

    // ---- tentative conf loss + smooth-L1 (no forced override) ----
    // __expf/__logf (native v_exp/v_log): MUST stay identical (same intrinsic,
    // same summation order) to the fixup recompute in select_kernel so the
    // fixup delta cancels bit-exactly against these tentative sums.
    float ll = 0.0f, pc = 0.0f;
    int np = 0;
    if (pv) {
        float m = rv[0];
#pragma unroll
        for (int j = 1; j < CC; ++j) { if (CN > 0 || j < C) m = fmaxf(m, rv[j]); }
        float s = 0.0f;
#pragma unroll
        for (int j = 0; j < CC; ++j) { if (CN > 0 || j < C) s += __expf(rv[j] - m); }
        float lse = m + __logf(s);

        int c = (bto < 0.5f) ? 0 : ((int)s_lab[bti] + 1);
        float rowc = rv[0];
#pragma unroll
        for (int j = 1; j < CC; ++j) { if (CN > 0 || j < C) { if (c == j) rowc = rv[j]; } }
        float lc = lse - rowc;  // >= 0 always (s >= 1)

        bool pos = c > 0;
        mined[(size_t)b * P + p] = pos ? 0.0f : lc;
        if (pos) {
            pc = lc;
            np = 1;
            float mx0 = s_tx0[bti], my0 = s_ty0[bti];
            float mx1 = s_tx1[bti], my1 = s_ty1[bti];
            float g0 = ((mx0 + mx1) * 0.5f - cx) / (0.1f * pw);
            float g1 = ((my0 + my1) * 0.5f - cy) / (0.1f * ph);
            float g2 = logf(fmaxf((mx1 - mx0) / pw, 1e-8f)) / 0.2f;
            float g3 = logf(fmaxf((my1 - my0) / ph, 1e-8f)) / 0.2f;
            float4 ld = ((const float4*)loc)[(size_t)b * P + p];
            float gt4[4] = {g0, g1, g2, g3};
            float lv[4] = {ld.x, ld.y, ld.z, ld.w};
#pragma unroll
            for (int q = 0; q < 4; ++q) {
                float d = lv[q] - gt4[q];
                float ad = fabsf(d);
                ll += (ad < 1.0f) ? 0.5f * d * d : (ad - 0.5f);
            }
        }
    }

#pragma unroll
    for (int d = 1; d < 64; d <<= 1) {
        ll += __shfl_xor(ll, d, 64);
        pc += __shfl_xor(pc, d, 64);
        np += __shfl_xor(np, d, 64);
    }
    if (lane == 0) { s_wll[wv] = ll; s_wpc[wv] = pc; s_wnp[wv] = np; }
    __syncthreads();
    if (tid == 0) {
        float L = 0.f, Pc = 0.f;
        int N = 0;
        for (int w = 0; w < TPB / 64; ++w) { L += s_wll[w]; Pc += s_wpc[w]; N += s_wnp[w]; }
        part_ll[blockIdx.x] = L;
        part_pc[blockIdx.x] = Pc;
        part_np[blockIdx.x] = N;
    }
}

// One 1024-thread block per batch. NO __threadfence / device counter (the
// R11 43-us constant stall): per-batch results are plain stores; a separate
// tiny finalize dispatch does the last 64-element reduction.
//  1. stage mined row into static LDS (coalesced; not scratch)
//  2. reduce per-chunk argmax keys -> bp[o]; zero forced priors in s_m
//  3. FIXUP (wave 0, <= O priors; dedup: largest o owns p = last-wins
//     scatter): recompute tentative contribution bit-identically, apply delta
//  4. radix-select k-th largest (values >= 0, bit-monotone).
//     Histogram layout is bin-major padded (s_hist[bin*HP + wv]) so the same
//     bin of different waves hits different banks; pass 0 (exponent byte,
//     ~4 distinct bins -> 64-deep same-address serialization otherwise) uses
//     wave-clustered atomics: ballot-group equal bins, leader adds popcount.
//     sum(top-k) = sum_{>T} + (k-cnt_gt)*T — exact under ties
template <int ON, int CN>
__global__ __launch_bounds__(TPBS) void select_kernel(
    const float* __restrict__ mined, const float* __restrict__ conf,
    const float* __restrict__ loc, const float* __restrict__ priors,
    const float* __restrict__ targets, const ull* __restrict__ pkeys,
    const float* __restrict__ part_ll, const float* __restrict__ part_pc,
    const int* __restrict__ part_np,
    float* __restrict__ ll_batch, float* __restrict__ lc_batch,
    int* __restrict__ np_batch,
    int P, int O_rt, int C_rt, int CB2, int ratio) {
    constexpr int OMAX = (ON > 0) ? ON : 64;
    const int O = (ON > 0) ? ON : O_rt;
    const int C = (CN > 0) ? CN : C_rt;
    const int b = blockIdx.x, tid = threadIdx.x;
    const int lane = tid & 63, wv = tid >> 6;
    constexpr int W = TPBS / 64;  // 16 waves
    const float* v = mined + (size_t)b * P;
    const bool lds = (P <= LDSF);

    __shared__ float s_m[LDSF];        // 48 KB staged row
    __shared__ int s_hist[256 * HP];   // 17 KB bin-major padded histograms
    __shared__ float s_tx0[OMAX], s_ty0[OMAX], s_tx1[OMAX], s_ty1[OMAX];
    __shared__ float s_lab[OMAX], s_area[OMAX];
    __shared__ ull s_keys[OMAX];
    __shared__ int s_bp[OMAX];
    __shared__ float s_wf[W], s_wg[W];
    __shared__ int s_wi[W];
    __shared__ int s_wt[4];
    __shared__ unsigned s_bsel;
    __shared__ int s_krn;
    __shared__ float s_bc[2], s_fix[2];
    __shared__ int s_bn, s_fixn;

    // 1. stage mined row; overlap: per-chunk tentative partial reduction
    if (lds) {
        for (int i = tid; i < P; i += TPBS) s_m[i] = v[i];
    }
    float pll = 0.0f, ppc = 0.0f;
    int pnp = 0;
    for (int i = tid; i < CB2; i += TPBS) {
        pll += part_ll[b * CB2 + i];
        ppc += part_pc[b * CB2 + i];
        pnp += part_np[b * CB2 + i];
    }
#pragma unroll
    for (int d = 1; d < 64; d <<= 1) {
        pll += __shfl_xor(pll, d, 64);
        ppc += __shfl_xor(ppc, d, 64);
        pnp += __shfl_xor(pnp, d, 64);
    }
    if (lane == 0) { s_wf[wv] = pll; s_wg[wv] = ppc; s_wi[wv] = pnp; }

    if (tid < O) {
        const float* t = targets + ((size_t)b * O + tid) * 5;
        float x0 = t[0], y0 = t[1], x1 = t[2], y1 = t[3];
        s_tx0[tid] = x0; s_ty0[tid] = y0; s_tx1[tid] = x1; s_ty1[tid] = y1;
        s_lab[tid] = t[4];
        s_area[tid] = (x1 - x0) * (y1 - y0);
        s_keys[tid] = 0ull;
    }
    __syncthreads();

    // 2. reduce per-chunk keys (block-local LDS atomics, O*CB2 entries)
    for (int i = tid; i < O * CB2; i += TPBS) {
        int o = i / CB2, s = i % CB2;
        atomicMax(&s_keys[o], pkeys[((size_t)b * O + o) * CB2 + s]);
    }
    __syncthreads();
    if (tid < O)
        s_bp[tid] = (int)(0xFFFFFFFFu - (unsigned)(s_keys[tid] & 0xFFFFFFFFull));
    __syncthreads();

    // zero forced priors in the staged row (they are positive -> mined 0;
    // concurrent same-value writes are benign)
    if (lds && tid < O) s_m[s_bp[tid]] = 0.0f;

    // 3. FIXUP deltas (wave-0 lanes; proven bit-exact in R9/R11).
    // lse recompute uses __expf/__logf in the SAME order as fused_kernel.
    float dll = 0.0f, dpc = 0.0f;
    int dnp = 0;
    if (tid < O) {
        const int o = tid;
        const int p = s_bp[o];
        bool owner = true;
        for (int o2 = o + 1; o2 < O; ++o2)
            if (s_bp[o2] == p) owner = false;  // largest o owns (last-wins scatter)
        if (owner) {
            float4 pr = ((const float4*)priors)[p];
            float cx = pr.x, cy = pr.y, pw = pr.z, ph = pr.w;
            float px0 = cx - pw * 0.5f, py0 = cy - ph * 0.5f;
            float px1 = cx + pw * 0.5f, py1 = cy + ph * 0.5f;
            float pa = (px1 - px0) * (py1 - py0);
            float bto = -1.0f;
            int bti = 0;
            for (int o2 = 0; o2 < O; ++o2) {
                float ov = jac(s_tx0[o2], s_ty0[o2], s_tx1[o2], s_ty1[o2], s_area[o2],
                               px0, py0, px1, py1, pa);
                if (ov > bto) { bto = ov; bti = o2; }
            }
            int c_t = (bto < 0.5f) ? 0 : ((int)s_lab[bti] + 1);
            const float* row = conf + ((size_t)b * P + p) * C;
            float m = row[0];
            for (int j = 1; j < C; ++j) m = fmaxf(m, row[j]);
            float s = 0.0f;
            for (int j = 0; j < C; ++j) s += __expf(row[j] - m);
            float lse = m + __logf(s);
            int c_n = (int)s_lab[o] + 1;
            float lc_n = lse - row[c_n];
            bool pos_t = c_t > 0;
            float lc_t = lse - row[c_t];
            dpc = lc_n - (pos_t ? lc_t : 0.0f);
            dnp = 1 - (pos_t ? 1 : 0);
            float4 ld = ((const float4*)loc)[(size_t)b * P + p];
            float lv[4] = {ld.x, ld.y, ld.z, ld.w};
            float sl_new = 0.0f, sl_old = 0.0f;
            {
                float mx0 = s_tx0[o], my0 = s_ty0[o], mx1 = s_tx1[o], my1 = s_ty1[o];
                float g[4] = {((mx0 + mx1) * 0.5f - cx) / (0.1f * pw),
                              ((my0 + my1) * 0.5f - cy) / (0.1f * ph),
                              logf(fmaxf((mx1 - mx0) / pw, 1e-8f)) / 0.2f,
                              logf(fmaxf((my1 - my0) / ph, 1e-8f)) / 0.2f};
                for (int q = 0; q < 4; ++q) {
                    float d = lv[q] - g[q];
                    float ad = fabsf(d);
                    sl_new += (ad < 1.0f) ? 0.5f * d * d : (ad - 0.5f);
                }
            }
            if (pos_t) {
                float mx0 = s_tx0[bti], my0 = s_ty0[bti], mx1 = s_tx1[bti], my1 = s_ty1[bti];
                float g[4] = {((mx0 + mx1) * 0.5f - cx) / (0.1f * pw),
                              ((my0 + my1) * 0.5f - cy) / (0.1f * ph),
                              logf(fmaxf((mx1 - mx0) / pw, 1e-8f)) / 0.2f,
                              logf(fmaxf((my1 - my0) / ph, 1e-8f)) / 0.2f};
                for (int q = 0; q < 4; ++q) {
                    float d = lv[q] - g[q];
                    float ad = fabsf(d);
                    sl_old += (ad < 1.0f) ? 0.5f * d * d : (ad - 0.5f);
                }
            }
            dll = sl_new - sl_old;
        }
    }
    if (wv == 0) {
#pragma unroll
        for (int d = 1; d < 64; d <<= 1) {
            dll += __shfl_xor(dll, d, 64);
            dpc += __shfl_xor(dpc, d, 64);
            dnp += __shfl_xor(dnp, d, 64);
        }
        if (lane == 0) { s_fix[0] = dll; s_fix[1] = dpc; s_fixn = dnp; }
    }
    __syncthreads();
    if (tid == 0) {
        float L = 0.f, Pc = 0.f;
        int N = 0;
        for (int w = 0; w < W; ++w) { L += s_wf[w]; Pc += s_wg[w]; N += s_wi[w]; }
        s_bc[0] = L + s_fix[0]; s_bc[1] = Pc + s_fix[1]; s_bn = N + s_fixn;
    }
    __syncthreads();
    const float ll_sum = s_bc[0];
    const float sum_pos = s_bc[1];
    const int npos = s_bn;

    const int k = min(ratio * npos, P - npos);
    if (tid == 0) {
        ll_batch[b] = ll_sum;
        np_batch[b] = npos;
    }
    if (k <= 0) {
        if (tid == 0) lc_batch[b] = sum_pos;
        return;
    }

    // 4. radix-select on the staged (and forced-zeroed) row
    unsigned prefix = 0u;
    int kr = k;
    for (int pass = 0; pass < 4; ++pass) {
        const int shift = 24 - 8 * pass;
        const unsigned mask = (pass == 0) ? 0u : (0xFFFFFFFFu << (32 - 8 * pass));
        for (int i = tid; i < 256 * HP; i += TPBS) s_hist[i] = 0;
        __syncthreads();
        for (int i = tid; i < P; i += TPBS) {
            float x;
            if (lds) x = s_m[i];
            else {
                x = v[i];
                for (int o = 0; o < O; ++o)
                    if (i == s_bp[o]) x = 0.0f;
            }
            unsigned u = __float_as_uint(x);
            bool match = ((u & mask) == prefix);
            int bin = (u >> shift) & 0xFF;
            if (pass == 0) {
                // wave-clustered add: exponent byte has few distinct values;
                // plain per-lane atomics would serialize ~64-deep same-address
                ull act = __ballot(match);
                while (act) {
                    int src = __ffsll(act) - 1;
                    int b0 = __shfl(bin, src, 64);
                    ull same = __ballot(match && bin == b0) & act;
                    if (lane == src)
                        atomicAdd(&s_hist[b0 * HP + wv], (int)__popcll(same));
                    act &= ~same;
                }
            } else if (match) {
                atomicAdd(&s_hist[bin * HP + wv], 1);
            }
        }
        __syncthreads();
        int sge = 0, h = 0;
        if (tid < 256) {
            for (int w = 0; w < W; ++w) h += s_hist[tid * HP + w];
            int val = h;
#pragma unroll
            for (int d = 1; d < 64; d <<= 1) {
                int t = __shfl_down(val, d, 64);
                if (lane + d < 64) val += t;
            }
            if (lane == 0) s_wt[tid >> 6] = val;
            sge = val;
        }
        __syncthreads();
        if (tid < 256) {
            for (int w = (tid >> 6) + 1; w < 4; ++w) sge += s_wt[w];
            int sgt = sge - h;
            if (sge >= kr && sgt < kr) {  // exactly one tid satisfies
                s_bsel = (unsigned)tid;
                s_krn = kr - sgt;
            }
        }
        __syncthreads();
        prefix |= s_bsel << shift;
        kr = s_krn;
        // no trailing barrier: s_bsel/s_krn next written only after two
        // barriers of the following pass
    }
    const float T = __uint_as_float(prefix);  // exact k-th largest value
    float lsum = 0.0f;
    int lcnt = 0;
    for (int i = tid; i < P; i += TPBS) {
        float x;
        if (lds) x = s_m[i];
        else {
            x = v[i];
            for (int o = 0; o < O; ++o)
                if (i == s_bp[o]) x = 0.0f;
        }
        if (x > T) { lsum += x; ++lcnt; }
    }
#pragma unroll
    for (int d = 1; d < 64; d <<= 1) {
        lsum += __shfl_xor(lsum, d, 64);
        lcnt += __shfl_xor(lcnt, d, 64);
    }
    if (lane == 0) { s_wf[wv] = lsum; s_wi[wv] = lcnt; }
    __syncthreads();
    if (tid == 0) {
        float S = 0.f;
        int Cn = 0;
        for (int w = 0; w < W; ++w) { S += s_wf[w]; Cn += s_wi[w]; }
        lc_batch[b] = sum_pos + S + (float)(k - Cn) * T;
    }
}

__global__ __launch_bounds__(TPB) void finalize_kernel(
    const float* __restrict__ ll_batch, const int* __restrict__ np_batch,
    const float* __restrict__ lc_batch, int B, float* __restrict__ out) {
    const int tid = threadIdx.x;
    __shared__ float s_l[TPB], s_c[TPB];
    __shared__ int s_n[TPB];
    float l = 0.0f, c = 0.0f;
    int n = 0;
    for (int i = tid; i < B; i += TPB) {
        l += ll_batch[i];
        c += lc_batch[i];
        n += np_batch[i];
    }
    s_l[tid] = l; s_c[tid] = c; s_n[tid] = n;
    __syncthreads();
    for (int s = TPB / 2; s > 0; s >>= 1) {
        if (tid < s) {
            s_l[tid] += s_l[tid + s];
            s_c[tid] += s_c[tid + s];
            s_n[tid] += s_n[tid + s];
        }
        __syncthreads();
    }
    if (tid == 0) {
        float N = (float)s_n[0];
        out[0] = s_l[0] / N;
        out[1] = s_c[0] / N;
    }
}

extern "C" void kernel_launch(void* const* d_in, const int* in_sizes, int n_in,
                              void* d_out, int out_size, void* d_ws, size_t ws_size,
                              hipStream_t stream) {
    const float* loc = (const float*)d_in[0];
    const float* conf = (const float*)d_in[1];
    const float* priors = (const float*)d_in[2];
    const float* targets = (const float*)d_in[3];

    const int P = in_sizes[2] / 4;
    const int B = in_sizes[0] / (P * 4);
    const int C = in_sizes[1] / (in_sizes[0] / 4);  // conf / (B*P)
    const int O = in_sizes[3] / (B * 5);
    const size_t BP = (size_t)B * P;
    const int CB2 = (P + TPB - 1) / TPB;   // chunks per batch

    // ws layout (8B-aligned first; everything fully written before read):
    ull* pkeys = (ull*)d_ws;                                // B*O*CB2 u64
    float* mined = (float*)(pkeys + (size_t)B * O * CB2);   // BP f32
    float* part_ll = mined + BP;                            // B*CB2 f32
    float* part_pc = part_ll + (size_t)B * CB2;             // B*CB2 f32
    int* part_np = (int*)(part_pc + (size_t)B * CB2);       // B*CB2 i32
    float* ll_batch = (float*)(part_np + (size_t)B * CB2);  // B f32
    float* lc_batch = ll_batch + B;                         // B f32
    int* np_batch = (int*)(lc_batch + B);                   // B i32

    if (O == 8 && C == 21) {
        fused_kernel<8, 21><<<B * CB2, TPB, 0, stream>>>(
            loc, priors, targets, conf, P, O, C, CB2,
            mined, pkeys, part_ll, part_pc, part_np);
        select_kernel<8, 21><<<B, TPBS, 0, stream>>>(
            mined, conf, loc, priors, targets, pkeys, part_ll, part_pc, part_np,
            ll_batch, lc_batch, np_batch, P, O, C, CB2, 3);
    } else {
        fused_kernel<0, 0><<<B * CB2, TPB, 0, stream>>>(
            loc, priors, targets, conf, P, O, C, CB2,
            mined, pkeys, part_ll, part_pc, part_np);
        select_kernel<0, 0><<<B, TPBS, 0, stream>>>(
            mined, conf, loc, priors, targets, pkeys, part_ll, part_pc, part_np,
            ll_batch, lc_batch, np_batch, P, O, C, CB2, 3);
    }

    finalize_kernel<<<1, TPB, 0, stream>>>(ll_batch, np_batch, lc_batch, B,
                                           (float*)d_out);
}

// Round 2
// 118.812 us; speedup vs baseline: 1.0544x; 1.0194x over previous
//
#include <hip/hip_runtime.h>
#include <math.h>

#define TPB 256
#define TPBS 1024    // select block size
#define LDSF 12288   // register-path capacity in floats (12 regs/thread)
#define HP 17        // hist stride: 16 waves + 1 pad (same bin spans 16 banks)

typedef unsigned long long ull;
typedef float pf4 __attribute__((ext_vector_type(4), aligned(4)));  // 4B-aligned float4

__device__ __forceinline__ float jac(float tx0, float ty0, float tx1, float ty1, float ta,
                                     float px0, float py0, float px1, float py1, float pa) {
    float ltx = fmaxf(tx0, px0), lty = fmaxf(ty0, py0);
    float rbx = fminf(tx1, px1), rby = fminf(ty1, py1);
    float w = fmaxf(rbx - ltx, 0.0f), h = fmaxf(rby - lty, 0.0f);
    float inter = w * h;
    return inter / (ta + pa - inter);
}

// ONE pass over all priors (grid B*CB2, thread-per-prior), producing:
//  - per-chunk per-o best-prior key partials (jac computed ONCE for both the
//    per-o argmax and the per-p sweep)
//  - TENTATIVE mined / smooth-L1 / positive sums (no forced-match override —
//    fixed up in select; proven bit-exact in R9/R11)
// Per-o argmax: f32 wave max-reduce + ballot; lowest lane with ov==mx gives
// the smallest p (reference first-max tiebreak). Cross-chunk key stays
// (ov_bits<<32) | (0xFFFFFFFF - p): ov >= 0 -> bit-monotone.
template <int ON, int CN>
__global__ __launch_bounds__(TPB) void fused_kernel(
    const float* __restrict__ loc, const float* __restrict__ priors,
    const float* __restrict__ targets, const float* __restrict__ conf,
    int P, int O_rt, int C_rt, int CB2,
    float* __restrict__ mined, ull* __restrict__ pkeys,
    float* __restrict__ part_ll, float* __restrict__ part_pc,
    int* __restrict__ part_np) {
    constexpr int OMAX = (ON > 0) ? ON : 64;
    constexpr int CC = (CN > 0) ? CN : 32;
    const int O = (ON > 0) ? ON : O_rt;
    const int C = (CN > 0) ? CN : C_rt;
    const int b = blockIdx.x / CB2;
    const int chunk = blockIdx.x % CB2;
    const int tid = threadIdx.x;
    const int p = chunk * TPB + tid;
    const bool pv = (p < P);
    const int lane = tid & 63, wv = tid >> 6;

    __shared__ float s_tx0[OMAX], s_ty0[OMAX], s_tx1[OMAX], s_ty1[OMAX];
    __shared__ float s_lab[OMAX], s_area[OMAX];
    __shared__ ull s_wk[TPB / 64][OMAX];
    __shared__ float s_wll[TPB / 64], s_wpc[TPB / 64];
    __shared__ int s_wnp[TPB / 64];

    // ---- issue conf-row + prior loads FIRST (latency overlaps setup) ----
    float rv[CC];
    float4 pr4 = make_float4(0.f, 0.f, 1.f, 1.f);
    if (pv) {
        const float* row = conf + ((size_t)b * P + p) * C;
        if (CN > 0) {
#pragma unroll
            for (int q = 0; q < CN / 4; ++q) {
                pf4 v = *(const pf4*)(row + 4 * q);
#pragma unroll
                for (int e = 0; e < 4; ++e) rv[4 * q + e] = v[e];
            }
#pragma unroll
            for (int j = (CN / 4) * 4; j < CN; ++j) rv[j] = row[j];
        } else {
            for (int j = 0; j < C; ++j) rv[j] = row[j];
        }
        pr4 = ((const float4*)priors)[p];
    }

    for (int o = tid; o < O; o += TPB) {
        const float* t = targets + ((size_t)b * O + o) * 5;
        float x0 = t[0], y0 = t[1], x1 = t[2], y1 = t[3];
        s_tx0[o] = x0; s_ty0[o] = y0; s_tx1[o] = x1; s_ty1[o] = y1;
        s_lab[o] = t[4];
        s_area[o] = (x1 - x0) * (y1 - y0);
    }
    __syncthreads();

    // ---- jac sweep: tentative per-p best (first-max over o) AND per-o
    //      wave argmax via f32 max-reduce + ballot (cheap; exact tiebreak) ----
    float cx = pr4.x, cy = pr4.y, pw = pr4.z, ph = pr4.w;
    float px0 = cx - pw * 0.5f, py0 = cy - ph * 0.5f;
    float px1 = cx + pw * 0.5f, py1 = cy + ph * 0.5f;
    float pa = (px1 - px0) * (py1 - py0);
    float bto = -1.0f;
    int bti = 0;
    for (int o = 0; o < O; ++o) {
        float ov = -1.0f;  // invalid lanes never win (mx >= 0 when any valid)
        if (pv) {
            ov = jac(s_tx0[o], s_ty0[o], s_tx1[o], s_ty1[o], s_area[o],
                     px0, py0, px1, py1, pa);
            if (ov > bto) { bto = ov; bti = o; }  // strictly > keeps earliest o
        }
        float mx = ov;
#pragma unroll
        for (int d = 1; d < 64; d <<= 1)
            mx = fmaxf(mx, __shfl_xor(mx, d, 64));
        ull kk = 0ull;
        if (mx >= 0.0f) {  // wave has at least one valid lane
            ull msk = __ballot(ov == mx);
            int src = __ffsll(msk) - 1;  // lowest lane = smallest p on ties
            unsigned pw_ = (unsigned)(chunk * TPB + (wv << 6) + src);
            kk = ((ull)__float_as_uint(mx) << 32) | (ull)(0xFFFFFFFFu - pw_);
        }
        if (lane == 0) s_wk[wv][o] = kk;
    }
    __syncthreads();
    if (tid < O) {
        ull kk = s_wk[0][tid];
        for (int w = 1; w < TPB / 64; ++w)
            if (s_wk[w][tid] > kk) kk = s_wk[w][tid];
        pkeys[((size_t)b * O + tid) * CB2 + chunk] = kk;
    }

    // ---- tentative conf loss + smooth-L1 (no forced override) ----
    // __expf/__logf: must stay identical (same intrinsic, same order) to the
    // fixup recompute in select_kernel so the delta cancels bit-exactly.
    float ll = 0.0f, pc = 0.0f;
    int np = 0;
    if (pv) {
        float m = rv[0];
#pragma unroll
        for (int j = 1; j < CC; ++j) { if (CN > 0 || j < C) m = fmaxf(m, rv[j]); }
        float s = 0.0f;
#pragma unroll
        for (int j = 0; j < CC; ++j) { if (CN > 0 || j < C) s += __expf(rv[j] - m); }
        float lse = m + __logf(s);

        int c = (bto < 0.5f) ? 0 : ((int)s_lab[bti] + 1);
        float rowc = rv[0];
#pragma unroll
        for (int j = 1; j < CC; ++j) { if (CN > 0 || j < C) { if (c == j) rowc = rv[j]; } }
        float lc = lse - rowc;  // >= 0 always (s >= 1)

        bool pos = c > 0;
        mined[(size_t)b * P + p] = pos ? 0.0f : lc;
        if (pos) {
            pc = lc;
            np = 1;
            float mx0 = s_tx0[bti], my0 = s_ty0[bti];
            float mx1 = s_tx1[bti], my1 = s_ty1[bti];
            float g0 = ((mx0 + mx1) * 0.5f - cx) / (0.1f * pw);
            float g1 = ((my0 + my1) * 0.5f - cy) / (0.1f * ph);
            float g2 = logf(fmaxf((mx1 - mx0) / pw, 1e-8f)) / 0.2f;
            float g3 = logf(fmaxf((my1 - my0) / ph, 1e-8f)) / 0.2f;
            float4 ld = ((const float4*)loc)[(size_t)b * P + p];
            float gt4[4] = {g0, g1, g2, g3};
            float lv[4] = {ld.x, ld.y, ld.z, ld.w};
#pragma unroll
            for (int q = 0; q < 4; ++q) {
                float d = lv[q] - gt4[q];
                float ad = fabsf(d);
                ll += (ad < 1.0f) ? 0.5f * d * d : (ad - 0.5f);
            }
        }
    }

#pragma unroll
    for (int d = 1; d < 64; d <<= 1) {
        ll += __shfl_xor(ll, d, 64);
        pc += __shfl_xor(pc, d, 64);
        np += __shfl_xor(np, d, 64);
    }
    if (lane == 0) { s_wll[wv] = ll; s_wpc[wv] = pc; s_wnp[wv] = np; }
    __syncthreads();
    if (tid == 0) {
        float L = 0.f, Pc = 0.f;
        int N = 0;
        for (int w = 0; w < TPB / 64; ++w) { L += s_wll[w]; Pc += s_wpc[w]; N += s_wnp[w]; }
        part_ll[blockIdx.x] = L;
        part_pc[blockIdx.x] = Pc;
        part_np[blockIdx.x] = N;
    }
}

// One 1024-thread block per batch. NO __threadfence / device counter (the
// R11 43-us constant stall): per-batch results are plain stores; a separate
// tiny finalize dispatch does the last 64-element reduction.
//  REGISTER-RESIDENT VALUES (R2): each thread owns indices tid + j*1024
//  (j < 12). The mined row is loaded ONCE into registers (issued at kernel
//  start, latency hidden under the part_*/key reductions), forced-zeroed in
//  registers, float-as-uint converted ONCE, and all 4 radix passes + the
//  final sum run on registers — no 48 KB LDS stage, no LDS value re-reads.
//  Same indices, same order, same zero rule as the staged version ->
//  bit-identical results.
//  Radix histograms: bin-major padded (s_hist[bin*HP + wv]); pass 0
//  (exponent byte, few distinct bins) uses wave-clustered atomics.
//  sum(top-k) = sum_{>T} + (k-cnt_gt)*T — exact under ties.
template <int ON, int CN>
__global__ __launch_bounds__(TPBS) void select_kernel(
    const float* __restrict__ mined, const float* __restrict__ conf,
    const float* __restrict__ loc, const float* __restrict__ priors,
    const float* __restrict__ targets, const ull* __restrict__ pkeys,
    const float* __restrict__ part_ll, const float* __restrict__ part_pc,
    const int* __restrict__ part_np,
    float* __restrict__ ll_batch, float* __restrict__ lc_batch,
    int* __restrict__ np_batch,
    int P, int O_rt, int C_rt, int CB2, int ratio) {
    constexpr int OMAX = (ON > 0) ? ON : 64;
    constexpr int NV = LDSF / TPBS;  // 12 register slots per thread
    const int O = (ON > 0) ? ON : O_rt;
    const int C = (CN > 0) ? CN : C_rt;
    const int b = blockIdx.x, tid = threadIdx.x;
    const int lane = tid & 63, wv = tid >> 6;
    constexpr int W = TPBS / 64;  // 16 waves
    const float* v = mined + (size_t)b * P;
    const bool reg = (P <= NV * TPBS);

    __shared__ int s_hist[256 * HP];   // 17 KB bin-major padded histograms
    __shared__ float s_tx0[OMAX], s_ty0[OMAX], s_tx1[OMAX], s_ty1[OMAX];
    __shared__ float s_lab[OMAX], s_area[OMAX];
    __shared__ ull s_keys[OMAX];
    __shared__ int s_bp[OMAX];
    __shared__ float s_wf[W], s_wg[W];
    __shared__ int s_wi[W];
    __shared__ int s_wt[4];
    __shared__ unsigned s_bsel;
    __shared__ int s_krn;
    __shared__ float s_bc[2], s_fix[2];
    __shared__ int s_bn, s_fixn;

    // 0. issue the row loads FIRST — latency hides under the reductions below
    float val[NV];
#pragma unroll
    for (int j = 0; j < NV; ++j) {
        int i = tid + j * TPBS;
        val[j] = (reg && i < P) ? v[i] : 0.0f;
    }

    // 1. per-chunk tentative partial reduction
    float pll = 0.0f, ppc = 0.0f;
    int pnp = 0;
    for (int i = tid; i < CB2; i += TPBS) {
        pll += part_ll[b * CB2 + i];
        ppc += part_pc[b * CB2 + i];
        pnp += part_np[b * CB2 + i];
    }
#pragma unroll
    for (int d = 1; d < 64; d <<= 1) {
        pll += __shfl_xor(pll, d, 64);
        ppc += __shfl_xor(ppc, d, 64);
        pnp += __shfl_xor(pnp, d, 64);
    }
    if (lane == 0) { s_wf[wv] = pll; s_wg[wv] = ppc; s_wi[wv] = pnp; }

    if (tid < O) {
        const float* t = targets + ((size_t)b * O + tid) * 5;
        float x0 = t[0], y0 = t[1], x1 = t[2], y1 = t[3];
        s_tx0[tid] = x0; s_ty0[tid] = y0; s_tx1[tid] = x1; s_ty1[tid] = y1;
        s_lab[tid] = t[4];
        s_area[tid] = (x1 - x0) * (y1 - y0);
        s_keys[tid] = 0ull;
    }
    __syncthreads();

    // 2. reduce per-chunk keys (block-local LDS atomics, O*CB2 entries)
    for (int i = tid; i < O * CB2; i += TPBS) {
        int o = i / CB2, s = i % CB2;
        atomicMax(&s_keys[o], pkeys[((size_t)b * O + o) * CB2 + s]);
    }
    __syncthreads();
    if (tid < O)
        s_bp[tid] = (int)(0xFFFFFFFFu - (unsigned)(s_keys[tid] & 0xFFFFFFFFull));
    __syncthreads();

    // zero forced priors in the register copy (forced -> positive -> mined 0)
    if (reg) {
#pragma unroll
        for (int j = 0; j < NV; ++j) {
            int i = tid + j * TPBS;
            bool z = false;
            for (int o = 0; o < O; ++o) z |= (s_bp[o] == i);
            if (z) val[j] = 0.0f;
        }
    }
    // one-time float->uint conversion for all radix passes
    unsigned uvv[NV];
#pragma unroll
    for (int j = 0; j < NV; ++j) uvv[j] = __float_as_uint(val[j]);

    // 3. FIXUP deltas (wave-0 lanes; proven bit-exact in R9/R11).
    float dll = 0.0f, dpc = 0.0f;
    int dnp = 0;
    if (tid < O) {
        const int o = tid;
        const int p = s_bp[o];
        bool owner = true;
        for (int o2 = o + 1; o2 < O; ++o2)
            if (s_bp[o2] == p) owner = false;  // largest o owns (last-wins scatter)
        if (owner) {
            float4 pr = ((const float4*)priors)[p];
            float cx = pr.x, cy = pr.y, pw = pr.z, ph = pr.w;
            float px0 = cx - pw * 0.5f, py0 = cy - ph * 0.5f;
            float px1 = cx + pw * 0.5f, py1 = cy + ph * 0.5f;
            float pa = (px1 - px0) * (py1 - py0);
            float bto = -1.0f;
            int bti = 0;
            for (int o2 = 0; o2 < O; ++o2) {
                float ov = jac(s_tx0[o2], s_ty0[o2], s_tx1[o2], s_ty1[o2], s_area[o2],
                               px0, py0, px1, py1, pa);
                if (ov > bto) { bto = ov; bti = o2; }
            }
            int c_t = (bto < 0.5f) ? 0 : ((int)s_lab[bti] + 1);
            const float* row = conf + ((size_t)b * P + p) * C;
            float m = row[0];
            for (int j = 1; j < C; ++j) m = fmaxf(m, row[j]);
            float s = 0.0f;
            for (int j = 0; j < C; ++j) s += __expf(row[j] - m);
            float lse = m + __logf(s);
            int c_n = (int)s_lab[o] + 1;
            float lc_n = lse - row[c_n];
            bool pos_t = c_t > 0;
            float lc_t = lse - row[c_t];
            dpc = lc_n - (pos_t ? lc_t : 0.0f);
            dnp = 1 - (pos_t ? 1 : 0);
            float4 ld = ((const float4*)loc)[(size_t)b * P + p];
            float lv[4] = {ld.x, ld.y, ld.z, ld.w};
            float sl_new = 0.0f, sl_old = 0.0f;
            {
                float mx0 = s_tx0[o], my0 = s_ty0[o], mx1 = s_tx1[o], my1 = s_ty1[o];
                float g[4] = {((mx0 + mx1) * 0.5f - cx) / (0.1f * pw),
                              ((my0 + my1) * 0.5f - cy) / (0.1f * ph),
                              logf(fmaxf((mx1 - mx0) / pw, 1e-8f)) / 0.2f,
                              logf(fmaxf((my1 - my0) / ph, 1e-8f)) / 0.2f};
                for (int q = 0; q < 4; ++q) {
                    float d = lv[q] - g[q];
                    float ad = fabsf(d);
                    sl_new += (ad < 1.0f) ? 0.5f * d * d : (ad - 0.5f);
                }
            }
            if (pos_t) {
                float mx0 = s_tx0[bti], my0 = s_ty0[bti], mx1 = s_tx1[bti], my1 = s_ty1[bti];
                float g[4] = {((mx0 + mx1) * 0.5f - cx) / (0.1f * pw),
                              ((my0 + my1) * 0.5f - cy) / (0.1f * ph),
                              logf(fmaxf((mx1 - mx0) / pw, 1e-8f)) / 0.2f,
                              logf(fmaxf((my1 - my0) / ph, 1e-8f)) / 0.2f};
                for (int q = 0; q < 4; ++q) {
                    float d = lv[q] - g[q];
                    float ad = fabsf(d);
                    sl_old += (ad < 1.0f) ? 0.5f * d * d : (ad - 0.5f);
                }
            }
            dll = sl_new - sl_old;
        }
    }
    if (wv == 0) {
#pragma unroll
        for (int d = 1; d < 64; d <<= 1) {
            dll += __shfl_xor(dll, d, 64);
            dpc += __shfl_xor(dpc, d, 64);
            dnp += __shfl_xor(dnp, d, 64);
        }
        if (lane == 0) { s_fix[0] = dll; s_fix[1] = dpc; s_fixn = dnp; }
    }
    __syncthreads();
    if (tid == 0) {
        float L = 0.f, Pc = 0.f;
        int N = 0;
        for (int w = 0; w < W; ++w) { L += s_wf[w]; Pc += s_wg[w]; N += s_wi[w]; }
        s_bc[0] = L + s_fix[0]; s_bc[1] = Pc + s_fix[1]; s_bn = N + s_fixn;
    }
    __syncthreads();
    const float ll_sum = s_bc[0];
    const float sum_pos = s_bc[1];
    const int npos = s_bn;

    const int k = min(ratio * npos, P - npos);
    if (tid == 0) {
        ll_batch[b] = ll_sum;
        np_batch[b] = npos;
    }
    if (k <= 0) {
        if (tid == 0) lc_batch[b] = sum_pos;
        return;
    }

    // 4. radix-select on the register copy
    unsigned prefix = 0u;
    int kr = k;
    for (int pass = 0; pass < 4; ++pass) {
        const int shift = 24 - 8 * pass;
        const unsigned mask = (pass == 0) ? 0u : (0xFFFFFFFFu << (32 - 8 * pass));
        for (int i = tid; i < 256 * HP; i += TPBS) s_hist[i] = 0;
        __syncthreads();
        if (reg) {
#pragma unroll
            for (int j = 0; j < NV; ++j) {
                int i = tid + j * TPBS;
                unsigned u = uvv[j];
                bool match = (i < P) && ((u & mask) == prefix);
                int bin = (u >> shift) & 0xFF;
                if (pass == 0) {
                    // wave-clustered add: exponent byte has few distinct values
                    ull act = __ballot(match);
                    while (act) {
                        int src = __ffsll(act) - 1;
                        int b0 = __shfl(bin, src, 64);
                        ull same = __ballot(match && bin == b0) & act;
                        if (lane == src)
                            atomicAdd(&s_hist[b0 * HP + wv], (int)__popcll(same));
                        act &= ~same;
                    }
                } else if (match) {
                    atomicAdd(&s_hist[bin * HP + wv], 1);
                }
            }
        } else {
            for (int i = tid; i < P; i += TPBS) {
                float x = v[i];
                for (int o = 0; o < O; ++o)
                    if (i == s_bp[o]) x = 0.0f;
                unsigned u = __float_as_uint(x);
                bool match = ((u & mask) == prefix);
                int bin = (u >> shift) & 0xFF;
                if (pass == 0) {
                    ull act = __ballot(match);
                    while (act) {
                        int src = __ffsll(act) - 1;
                        int b0 = __shfl(bin, src, 64);
                        ull same = __ballot(match && bin == b0) & act;
                        if (lane == src)
                            atomicAdd(&s_hist[b0 * HP + wv], (int)__popcll(same));
                        act &= ~same;
                    }
                } else if (match) {
                    atomicAdd(&s_hist[bin * HP + wv], 1);
                }
            }
        }
        __syncthreads();
        int sge = 0, h = 0;
        if (tid < 256) {
            for (int w = 0; w < W; ++w) h += s_hist[tid * HP + w];
            int val_ = h;
#pragma unroll
            for (int d = 1; d < 64; d <<= 1) {
                int t = __shfl_down(val_, d, 64);
                if (lane + d < 64) val_ += t;
            }
            if (lane == 0) s_wt[tid >> 6] = val_;
            sge = val_;
        }
        __syncthreads();
        if (tid < 256) {
            for (int w = (tid >> 6) + 1; w < 4; ++w) sge += s_wt[w];
            int sgt = sge - h;
            if (sge >= kr && sgt < kr) {  // exactly one tid satisfies
                s_bsel = (unsigned)tid;
                s_krn = kr - sgt;
            }
        }
        __syncthreads();
        prefix |= s_bsel << shift;
        kr = s_krn;
        // no trailing barrier: s_bsel/s_krn next written only after two
        // barriers of the following pass
    }
    const float T = __uint_as_float(prefix);  // exact k-th largest value
    float lsum = 0.0f;
    int lcnt = 0;
    if (reg) {
#pragma unroll
        for (int j = 0; j < NV; ++j) {
            int i = tid + j * TPBS;
            if (i < P && val[j] > T) { lsum += val[j]; ++lcnt; }
        }
    } else {
        for (int i = tid; i < P; i += TPBS) {
            float x = v[i];
            for (int o = 0; o < O; ++o)
                if (i == s_bp[o]) x = 0.0f;
            if (x > T) { lsum += x; ++lcnt; }
        }
    }
#pragma unroll
    for (int d = 1; d < 64; d <<= 1) {
        lsum += __shfl_xor(lsum, d, 64);
        lcnt += __shfl_xor(lcnt, d, 64);
    }
    if (lane == 0) { s_wf[wv] = lsum; s_wi[wv] = lcnt; }
    __syncthreads();
    if (tid == 0) {
        float S = 0.f;
        int Cn = 0;
        for (int w = 0; w < W; ++w) { S += s_wf[w]; Cn += s_wi[w]; }
        lc_batch[b] = sum_pos + S + (float)(k - Cn) * T;
    }
}

__global__ __launch_bounds__(TPB) void finalize_kernel(
    const float* __restrict__ ll_batch, const int* __restrict__ np_batch,
    const float* __restrict__ lc_batch, int B, float* __restrict__ out) {
    const int tid = threadIdx.x;
    __shared__ float s_l[TPB], s_c[TPB];
    __shared__ int s_n[TPB];
    float l = 0.0f, c = 0.0f;
    int n = 0;
    for (int i = tid; i < B; i += TPB) {
        l += ll_batch[i];
        c += lc_batch[i];
        n += np_batch[i];
    }
    s_l[tid] = l; s_c[tid] = c; s_n[tid] = n;
    __syncthreads();
    for (int s = TPB / 2; s > 0; s >>= 1) {
        if (tid < s) {
            s_l[tid] += s_l[tid + s];
            s_c[tid] += s_c[tid + s];
            s_n[tid] += s_n[tid + s];
        }
        __syncthreads();
    }
    if (tid == 0) {
        float N = (float)s_n[0];
        out[0] = s_l[0] / N;
        out[1] = s_c[0] / N;
    }
}

extern "C" void kernel_launch(void* const* d_in, const int* in_sizes, int n_in,
                              void* d_out, int out_size, void* d_ws, size_t ws_size,
                              hipStream_t stream) {
    const float* loc = (const float*)d_in[0];
    const float* conf = (const float*)d_in[1];
    const float* priors = (const float*)d_in[2];
    const float* targets = (const float*)d_in[3];

    const int P = in_sizes[2] / 4;
    const int B = in_sizes[0] / (P * 4);
    const int C = in_sizes[1] / (in_sizes[0] / 4);  // conf / (B*P)
    const int O = in_sizes[3] / (B * 5);
    const size_t BP = (size_t)B * P;
    const int CB2 = (P + TPB - 1) / TPB;   // chunks per batch

    // ws layout (8B-aligned first; everything fully written before read):
    ull* pkeys = (ull*)d_ws;                                // B*O*CB2 u64
    float* mined = (float*)(pkeys + (size_t)B * O * CB2);   // BP f32
    float* part_ll = mined + BP;                            // B*CB2 f32
    float* part_pc = part_ll + (size_t)B * CB2;             // B*CB2 f32
    int* part_np = (int*)(part_pc + (size_t)B * CB2);       // B*CB2 i32
    float* ll_batch = (float*)(part_np + (size_t)B * CB2);  // B f32
    float* lc_batch = ll_batch + B;                         // B f32
    int* np_batch = (int*)(lc_batch + B);                   // B i32

    if (O == 8 && C == 21) {
        fused_kernel<8, 21><<<B * CB2, TPB, 0, stream>>>(
            loc, priors, targets, conf, P, O, C, CB2,
            mined, pkeys, part_ll, part_pc, part_np);
        select_kernel<8, 21><<<B, TPBS, 0, stream>>>(
            mined, conf, loc, priors, targets, pkeys, part_ll, part_pc, part_np,
            ll_batch, lc_batch, np_batch, P, O, C, CB2, 3);
    } else {
        fused_kernel<0, 0><<<B * CB2, TPB, 0, stream>>>(
            loc, priors, targets, conf, P, O, C, CB2,
            mined, pkeys, part_ll, part_pc, part_np);
        select_kernel<0, 0><<<B, TPBS, 0, stream>>>(
            mined, conf, loc, priors, targets, pkeys, part_ll, part_pc, part_np,
            ll_batch, lc_batch, np_batch, P, O, C, CB2, 3);
    }

    finalize_kernel<<<1, TPB, 0, stream>>>(ll_batch, np_batch, lc_batch, B,
                                           (float*)d_out);
}

// Round 3
// 117.872 us; speedup vs baseline: 1.0628x; 1.0080x over previous
//
#include <hip/hip_runtime.h>
#include <math.h>

#define TPB 256
#define TPBS 1024    // select block size
#define NVREG 9      // register slots/thread in select (covers P <= 9216)

typedef unsigned long long ull;
typedef float pf4 __attribute__((ext_vector_type(4), aligned(4)));  // 4B-aligned float4

__device__ __forceinline__ float jac(float tx0, float ty0, float tx1, float ty1, float ta,
                                     float px0, float py0, float px1, float py1, float pa) {
    float ltx = fmaxf(tx0, px0), lty = fmaxf(ty0, py0);
    float rbx = fminf(tx1, px1), rby = fminf(ty1, py1);
    float w = fmaxf(rbx - ltx, 0.0f), h = fmaxf(rby - lty, 0.0f);
    float inter = w * h;
    return inter / (ta + pa - inter);
}

// ONE pass over all priors (grid B*CB2, thread-per-prior), producing:
//  - per-WAVE per-o best-prior keys straight to global (select's atomicMax
//    merge is associative -> identical result, one less barrier here)
//  - TENTATIVE mined / smooth-L1 / positive sums (forced-match override
//    fixed up in select; proven bit-exact R9/R11)
//  - R3: per-chunk 256-bin TOP-BYTE histogram of the tentative mined value
//    (u16-pair packed into 128 u32) — this removes select's full-P radix
//    pass 0 entirely.
template <int ON, int CN>
__global__ __launch_bounds__(TPB) void fused_kernel(
    const float* __restrict__ loc, const float* __restrict__ priors,
    const float* __restrict__ targets, const float* __restrict__ conf,
    int P, int O_rt, int C_rt, int CB2,
    float* __restrict__ mined, ull* __restrict__ pkeys,
    float* __restrict__ part_ll, float* __restrict__ part_pc,
    int* __restrict__ part_np, unsigned* __restrict__ chist) {
    constexpr int OMAX = (ON > 0) ? ON : 64;
    constexpr int CC = (CN > 0) ? CN : 32;
    constexpr int WPB = TPB / 64;  // waves per block
    const int O = (ON > 0) ? ON : O_rt;
    const int C = (CN > 0) ? CN : C_rt;
    const int b = blockIdx.x / CB2;
    const int chunk = blockIdx.x % CB2;
    const int tid = threadIdx.x;
    const int p = chunk * TPB + tid;
    const bool pv = (p < P);
    const int lane = tid & 63, wv = tid >> 6;
    const int CB2W = CB2 * WPB;

    __shared__ float s_tx0[OMAX], s_ty0[OMAX], s_tx1[OMAX], s_ty1[OMAX];
    __shared__ float s_lab[OMAX], s_area[OMAX];
    __shared__ int s_h[256];
    __shared__ float s_wll[WPB], s_wpc[WPB];
    __shared__ int s_wnp[WPB];

    // ---- issue conf-row + prior loads FIRST (latency overlaps setup) ----
    float rv[CC];
    float4 pr4 = make_float4(0.f, 0.f, 1.f, 1.f);
    if (pv) {
        const float* row = conf + ((size_t)b * P + p) * C;
        if (CN > 0) {
#pragma unroll
            for (int q = 0; q < CN / 4; ++q) {
                pf4 v = *(const pf4*)(row + 4 * q);
#pragma unroll
                for (int e = 0; e < 4; ++e) rv[4 * q + e] = v[e];
            }
#pragma unroll
            for (int j = (CN / 4) * 4; j < CN; ++j) rv[j] = row[j];
        } else {
            for (int j = 0; j < C; ++j) rv[j] = row[j];
        }
        pr4 = ((const float4*)priors)[p];
    }

    s_h[tid] = 0;  // TPB == 256: one bin each
    for (int o = tid; o < O; o += TPB) {
        const float* t = targets + ((size_t)b * O + o) * 5;
        float x0 = t[0], y0 = t[1], x1 = t[2], y1 = t[3];
        s_tx0[o] = x0; s_ty0[o] = y0; s_tx1[o] = x1; s_ty1[o] = y1;
        s_lab[o] = t[4];
        s_area[o] = (x1 - x0) * (y1 - y0);
    }
    __syncthreads();

    // ---- jac sweep: tentative per-p best (first-max over o) AND per-o
    //      wave argmax via f32 max-reduce + ballot; lane0 -> global key ----
    float cx = pr4.x, cy = pr4.y, pw = pr4.z, ph = pr4.w;
    float px0 = cx - pw * 0.5f, py0 = cy - ph * 0.5f;
    float px1 = cx + pw * 0.5f, py1 = cy + ph * 0.5f;
    float pa = (px1 - px0) * (py1 - py0);
    float bto = -1.0f;
    int bti = 0;
    for (int o = 0; o < O; ++o) {
        float ov = -1.0f;  // invalid lanes never win (mx >= 0 when any valid)
        if (pv) {
            ov = jac(s_tx0[o], s_ty0[o], s_tx1[o], s_ty1[o], s_area[o],
                     px0, py0, px1, py1, pa);
            if (ov > bto) { bto = ov; bti = o; }  // strictly > keeps earliest o
        }
        float mx = ov;
#pragma unroll
        for (int d = 1; d < 64; d <<= 1)
            mx = fmaxf(mx, __shfl_xor(mx, d, 64));
        ull kk = 0ull;
        if (mx >= 0.0f) {  // wave has at least one valid lane
            ull msk = __ballot(ov == mx);
            int src = __ffsll(msk) - 1;  // lowest lane = smallest p on ties
            unsigned pw_ = (unsigned)(chunk * TPB + (wv << 6) + src);
            kk = ((ull)__float_as_uint(mx) << 32) | (ull)(0xFFFFFFFFu - pw_);
        }
        if (lane == 0)
            pkeys[((size_t)b * O + o) * CB2W + chunk * WPB + wv] = kk;
    }

    // ---- tentative conf loss + smooth-L1 (no forced override) ----
    // __expf/__logf: must stay identical (same intrinsic, same order) to the
    // fixup recompute in select_kernel so the delta cancels bit-exactly.
    float ll = 0.0f, pc = 0.0f;
    int np = 0;
    int bin = 0;
    bool hv = false;
    if (pv) {
        float m = rv[0];
#pragma unroll
        for (int j = 1; j < CC; ++j) { if (CN > 0 || j < C) m = fmaxf(m, rv[j]); }
        float s = 0.0f;
#pragma unroll
        for (int j = 0; j < CC; ++j) { if (CN > 0 || j < C) s += __expf(rv[j] - m); }
        float lse = m + __logf(s);

        int c = (bto < 0.5f) ? 0 : ((int)s_lab[bti] + 1);
        float rowc = rv[0];
#pragma unroll
        for (int j = 1; j < CC; ++j) { if (CN > 0 || j < C) { if (c == j) rowc = rv[j]; } }
        float lc = lse - rowc;  // >= 0 always (s >= 1)

        bool pos = c > 0;
        float mv = pos ? 0.0f : lc;
        mined[(size_t)b * P + p] = mv;
        bin = (int)(__float_as_uint(mv) >> 24);
        hv = true;
        if (pos) {
            pc = lc;
            np = 1;
            float mx0 = s_tx0[bti], my0 = s_ty0[bti];
            float mx1 = s_tx1[bti], my1 = s_ty1[bti];
            float g0 = ((mx0 + mx1) * 0.5f - cx) / (0.1f * pw);
            float g1 = ((my0 + my1) * 0.5f - cy) / (0.1f * ph);
            float g2 = logf(fmaxf((mx1 - mx0) / pw, 1e-8f)) / 0.2f;
            float g3 = logf(fmaxf((my1 - my0) / ph, 1e-8f)) / 0.2f;
            float4 ld = ((const float4*)loc)[(size_t)b * P + p];
            float gt4[4] = {g0, g1, g2, g3};
            float lv[4] = {ld.x, ld.y, ld.z, ld.w};
#pragma unroll
            for (int q = 0; q < 4; ++q) {
                float d = lv[q] - gt4[q];
                float ad = fabsf(d);
                ll += (ad < 1.0f) ? 0.5f * d * d : (ad - 0.5f);
            }
        }
    }

    // top-byte histogram: wave-clustered LDS atomics (~5 distinct bins/wave)
    {
        ull act = __ballot(hv);
        while (act) {
            int src = __ffsll(act) - 1;
            int b0 = __shfl(bin, src, 64);
            ull same = __ballot(hv && bin == b0) & act;
            if (lane == src) atomicAdd(&s_h[b0], (int)__popcll(same));
            act &= ~same;
        }
    }

#pragma unroll
    for (int d = 1; d < 64; d <<= 1) {
        ll += __shfl_xor(ll, d, 64);
        pc += __shfl_xor(pc, d, 64);
        np += __shfl_xor(np, d, 64);
    }
    if (lane == 0) { s_wll[wv] = ll; s_wpc[wv] = pc; s_wnp[wv] = np; }
    __syncthreads();
    if (tid == 0) {
        float L = 0.f, Pc = 0.f;
        int N = 0;
        for (int w = 0; w < WPB; ++w) { L += s_wll[w]; Pc += s_wpc[w]; N += s_wnp[w]; }
        part_ll[blockIdx.x] = L;
        part_pc[blockIdx.x] = Pc;
        part_np[blockIdx.x] = N;
    }
    if (tid < 128) {
        unsigned wd = (unsigned)s_h[2 * tid] | ((unsigned)s_h[2 * tid + 1] << 16);
        chist[((size_t)b * CB2 + chunk) * 128 + tid] = wd;
    }
}

// One 1024-thread block per batch. NO __threadfence / device counter (the
// R11 43-us constant stall): per-batch results are plain stores; a separate
// tiny finalize dispatch does the last 64-element reduction.
//  Values register-resident (R2): thread owns indices tid + j*1024, j<9.
//  R3: radix pass 0 comes precomputed from fused's per-chunk top-byte
//  histograms (summed here + forced-zero adjusted -> bit-identical counts);
//  passes 1-3 use a single 256-int hist with plain atomics (mantissa bytes
//  spread) and direct s_hist[tid] scan reads.
//  sum(top-k) = sum_{>T} + (k-cnt_gt)*T — exact under ties.
template <int ON, int CN>
__global__ __launch_bounds__(TPBS) void select_kernel(
    const float* __restrict__ mined, const float* __restrict__ conf,
    const float* __restrict__ loc, const float* __restrict__ priors,
    const float* __restrict__ targets, const ull* __restrict__ pkeys,
    const float* __restrict__ part_ll, const float* __restrict__ part_pc,
    const int* __restrict__ part_np, const unsigned* __restrict__ chist,
    float* __restrict__ ll_batch, float* __restrict__ lc_batch,
    int* __restrict__ np_batch,
    int P, int O_rt, int C_rt, int CB2, int ratio) {
    constexpr int OMAX = (ON > 0) ? ON : 64;
    constexpr int NV = NVREG;
    const int O = (ON > 0) ? ON : O_rt;
    const int C = (CN > 0) ? CN : C_rt;
    const int b = blockIdx.x, tid = threadIdx.x;
    const int lane = tid & 63, wv = tid >> 6;
    constexpr int W = TPBS / 64;  // 16 waves
    const int CB2W = CB2 * (TPB / 64);
    const float* v = mined + (size_t)b * P;
    const bool reg = (P <= NV * TPBS);

    __shared__ int s_hist[256];
    __shared__ float s_tx0[OMAX], s_ty0[OMAX], s_tx1[OMAX], s_ty1[OMAX];
    __shared__ float s_lab[OMAX], s_area[OMAX];
    __shared__ ull s_keys[OMAX];
    __shared__ int s_bp[OMAX];
    __shared__ float s_wf[W], s_wg[W];
    __shared__ int s_wi[W];
    __shared__ int s_wt[4];
    __shared__ unsigned s_bsel;
    __shared__ int s_krn;
    __shared__ float s_bc[2], s_fix[2];
    __shared__ int s_bn, s_fixn;

    // 0. issue the row loads FIRST — latency hides under the reductions below
    float val[NV];
#pragma unroll
    for (int j = 0; j < NV; ++j) {
        int i = tid + j * TPBS;
        val[j] = (reg && i < P) ? v[i] : 0.0f;
    }

    // 1. per-chunk tentative partial reduction
    float pll = 0.0f, ppc = 0.0f;
    int pnp = 0;
    for (int i = tid; i < CB2; i += TPBS) {
        pll += part_ll[b * CB2 + i];
        ppc += part_pc[b * CB2 + i];
        pnp += part_np[b * CB2 + i];
    }
#pragma unroll
    for (int d = 1; d < 64; d <<= 1) {
        pll += __shfl_xor(pll, d, 64);
        ppc += __shfl_xor(ppc, d, 64);
        pnp += __shfl_xor(pnp, d, 64);
    }
    if (lane == 0) { s_wf[wv] = pll; s_wg[wv] = ppc; s_wi[wv] = pnp; }

    if (tid < O) {
        const float* t = targets + ((size_t)b * O + tid) * 5;
        float x0 = t[0], y0 = t[1], x1 = t[2], y1 = t[3];
        s_tx0[tid] = x0; s_ty0[tid] = y0; s_tx1[tid] = x1; s_ty1[tid] = y1;
        s_lab[tid] = t[4];
        s_area[tid] = (x1 - x0) * (y1 - y0);
        s_keys[tid] = 0ull;
    }
    __syncthreads();

    // 2. reduce per-wave keys (block-local LDS atomics, O*CB2W entries)
    for (int i = tid; i < O * CB2W; i += TPBS) {
        int o = i / CB2W, s = i % CB2W;
        atomicMax(&s_keys[o], pkeys[((size_t)b * O + o) * CB2W + s]);
    }
    __syncthreads();
    if (tid < O)
        s_bp[tid] = (int)(0xFFFFFFFFu - (unsigned)(s_keys[tid] & 0xFFFFFFFFull));
    __syncthreads();

    // zero forced priors in the register copy (forced -> positive -> mined 0)
    if (reg) {
#pragma unroll
        for (int j = 0; j < NV; ++j) {
            int i = tid + j * TPBS;
            bool z = false;
            for (int o = 0; o < O; ++o) z |= (s_bp[o] == i);
            if (z) val[j] = 0.0f;
        }
    }
    // one-time float->uint conversion for all radix passes
    unsigned uvv[NV];
#pragma unroll
    for (int j = 0; j < NV; ++j) uvv[j] = __float_as_uint(val[j]);

    // 2b. sum per-chunk top-byte histograms (bin = tid, u16 pair packed)
    if (tid < 256) {
        int h = 0;
        const unsigned* cb = chist + (size_t)b * CB2 * 128 + (tid >> 1);
        const int sh = (tid & 1) * 16;
        for (int c = 0; c < CB2; ++c) h += (int)((cb[c * 128] >> sh) & 0xFFFFu);
        s_hist[tid] = h;
    }

    // 3. FIXUP deltas (wave-0 lanes; proven bit-exact in R9/R11).
    float dll = 0.0f, dpc = 0.0f;
    int dnp = 0;
    int adj_bin = -1;  // hist adjustment: tentative value's top byte
    if (tid < O) {
        const int o = tid;
        const int p = s_bp[o];
        bool owner = true;
        for (int o2 = o + 1; o2 < O; ++o2)
            if (s_bp[o2] == p) owner = false;  // largest o owns (last-wins scatter)
        if (owner) {
            adj_bin = (int)(__float_as_uint(v[p]) >> 24);
            float4 pr = ((const float4*)priors)[p];
            float cx = pr.x, cy = pr.y, pw = pr.z, ph = pr.w;
            float px0 = cx - pw * 0.5f, py0 = cy - ph * 0.5f;
            float px1 = cx + pw * 0.5f, py1 = cy + ph * 0.5f;
            float pa = (px1 - px0) * (py1 - py0);
            float bto = -1.0f;
            int bti = 0;
            for (int o2 = 0; o2 < O; ++o2) {
                float ov = jac(s_tx0[o2], s_ty0[o2], s_tx1[o2], s_ty1[o2], s_area[o2],
                               px0, py0, px1, py1, pa);
                if (ov > bto) { bto = ov; bti = o2; }
            }
            int c_t = (bto < 0.5f) ? 0 : ((int)s_lab[bti] + 1);
            const float* row = conf + ((size_t)b * P + p) * C;
            float m = row[0];
            for (int j = 1; j < C; ++j) m = fmaxf(m, row[j]);
            float s = 0.0f;
            for (int j = 0; j < C; ++j) s += __expf(row[j] - m);
            float lse = m + __logf(s);
            int c_n = (int)s_lab[o] + 1;
            float lc_n = lse - row[c_n];
            bool pos_t = c_t > 0;
            float lc_t = lse - row[c_t];
            dpc = lc_n - (pos_t ? lc_t : 0.0f);
            dnp = 1 - (pos_t ? 1 : 0);
            float4 ld = ((const float4*)loc)[(size_t)b * P + p];
            float lv[4] = {ld.x, ld.y, ld.z, ld.w};
            float sl_new = 0.0f, sl_old = 0.0f;
            {
                float mx0 = s_tx0[o], my0 = s_ty0[o], mx1 = s_tx1[o], my1 = s_ty1[o];
                float g[4] = {((mx0 + mx1) * 0.5f - cx) / (0.1f * pw),
                              ((my0 + my1) * 0.5f - cy) / (0.1f * ph),
                              logf(fmaxf((mx1 - mx0) / pw, 1e-8f)) / 0.2f,
                              logf(fmaxf((my1 - my0) / ph, 1e-8f)) / 0.2f};
                for (int q = 0; q < 4; ++q) {
                    float d = lv[q] - g[q];
                    float ad = fabsf(d);
                    sl_new += (ad < 1.0f) ? 0.5f * d * d : (ad - 0.5f);
                }
            }
            if (pos_t) {
                float mx0 = s_tx0[bti], my0 = s_ty0[bti], mx1 = s_tx1[bti], my1 = s_ty1[bti];
                float g[4] = {((mx0 + mx1) * 0.5f - cx) / (0.1f * pw),
                              ((my0 + my1) * 0.5f - cy) / (0.1f * ph),
                              logf(fmaxf((mx1 - mx0) / pw, 1e-8f)) / 0.2f,
                              logf(fmaxf((my1 - my0) / ph, 1e-8f)) / 0.2f};
                for (int q = 0; q < 4; ++q) {
                    float d = lv[q] - g[q];
                    float ad = fabsf(d);
                    sl_old += (ad < 1.0f) ? 0.5f * d * d : (ad - 0.5f);
                }
            }
            dll = sl_new - sl_old;
        }
    }
    if (wv == 0) {
#pragma unroll
        for (int d = 1; d < 64; d <<= 1) {
            dll += __shfl_xor(dll, d, 64);
            dpc += __shfl_xor(dpc, d, 64);
            dnp += __shfl_xor(dnp, d, 64);
        }
        if (lane == 0) { s_fix[0] = dll; s_fix[1] = dpc; s_fixn = dnp; }
    }
    __syncthreads();
    // forced-zero hist adjustment (owners; matches zeroed registers exactly)
    if (adj_bin > 0) {  // adj_bin==0: -1/+1 on bin 0 cancels, skip
        atomicAdd(&s_hist[adj_bin], -1);
        atomicAdd(&s_hist[0], 1);
    }
    if (tid == 0) {
        float L = 0.f, Pc = 0.f;
        int N = 0;
        for (int w = 0; w < W; ++w) { L += s_wf[w]; Pc += s_wg[w]; N += s_wi[w]; }
        s_bc[0] = L + s_fix[0]; s_bc[1] = Pc + s_fix[1]; s_bn = N + s_fixn;
    }
    __syncthreads();
    const float ll_sum = s_bc[0];
    const float sum_pos = s_bc[1];
    const int npos = s_bn;

    const int k = min(ratio * npos, P - npos);
    if (tid == 0) {
        ll_batch[b] = ll_sum;
        np_batch[b] = npos;
    }
    if (k <= 0) {
        if (tid == 0) lc_batch[b] = sum_pos;
        return;
    }

    // 4. radix-select: pass 0 scan uses the precomputed+adjusted hist;
    //    passes 1-3 build a fresh single hist from the register copy.
    unsigned prefix = 0u;
    int kr = k;
    for (int pass = 0; pass < 4; ++pass) {
        const int shift = 24 - 8 * pass;
        if (pass > 0) {
            const unsigned mask = 0xFFFFFFFFu << (32 - 8 * pass);
            if (tid < 256) s_hist[tid] = 0;
            __syncthreads();
            if (reg) {
#pragma unroll
                for (int j = 0; j < NV; ++j) {
                    int i = tid + j * TPBS;
                    unsigned u = uvv[j];
                    if (i < P && (u & mask) == prefix)
                        atomicAdd(&s_hist[(u >> shift) & 0xFF], 1);
                }
            } else {
                for (int i = tid; i < P; i += TPBS) {
                    float x = v[i];
                    for (int o = 0; o < O; ++o)
                        if (i == s_bp[o]) x = 0.0f;
                    unsigned u = __float_as_uint(x);
                    if ((u & mask) == prefix)
                        atomicAdd(&s_hist[(u >> shift) & 0xFF], 1);
                }
            }
            __syncthreads();
        }
        int sge = 0, h = 0;
        if (tid < 256) {
            h = s_hist[tid];
            int val_ = h;
#pragma unroll
            for (int d = 1; d < 64; d <<= 1) {
                int t = __shfl_down(val_, d, 64);
                if (lane + d < 64) val_ += t;
            }
            if (lane == 0) s_wt[tid >> 6] = val_;
            sge = val_;
        }
        __syncthreads();
        if (tid < 256) {
            for (int w = (tid >> 6) + 1; w < 4; ++w) sge += s_wt[w];
            int sgt = sge - h;
            if (sge >= kr && sgt < kr) {  // exactly one tid satisfies
                s_bsel = (unsigned)tid;
                s_krn = kr - sgt;
            }
        }
        __syncthreads();
        prefix |= s_bsel << shift;
        kr = s_krn;
        // next pass's clear happens after a barrier; s_bsel/s_krn rewritten
        // only after two more barriers — no hazard
    }
    const float T = __uint_as_float(prefix);  // exact k-th largest value
    float lsum = 0.0f;
    int lcnt = 0;
    if (reg) {
#pragma unroll
        for (int j = 0; j < NV; ++j) {
            int i = tid + j * TPBS;
            if (i < P && val[j] > T) { lsum += val[j]; ++lcnt; }
        }
    } else {
        for (int i = tid; i < P; i += TPBS) {
            float x = v[i];
            for (int o = 0; o < O; ++o)
                if (i == s_bp[o]) x = 0.0f;
            if (x > T) { lsum += x; ++lcnt; }
        }
    }
#pragma unroll
    for (int d = 1; d < 64; d <<= 1) {
        lsum += __shfl_xor(lsum, d, 64);
        lcnt += __shfl_xor(lcnt, d, 64);
    }
    if (lane == 0) { s_wf[wv] = lsum; s_wi[wv] = lcnt; }
    __syncthreads();
    if (tid == 0) {
        float S = 0.f;
        int Cn = 0;
        for (int w = 0; w < W; ++w) { S += s_wf[w]; Cn += s_wi[w]; }
        lc_batch[b] = sum_pos + S + (float)(k - Cn) * T;
    }
}

__global__ __launch_bounds__(TPB) void finalize_kernel(
    const float* __restrict__ ll_batch, const int* __restrict__ np_batch,
    const float* __restrict__ lc_batch, int B, float* __restrict__ out) {
    const int tid = threadIdx.x;
    __shared__ float s_l[TPB], s_c[TPB];
    __shared__ int s_n[TPB];
    float l = 0.0f, c = 0.0f;
    int n = 0;
    for (int i = tid; i < B; i += TPB) {
        l += ll_batch[i];
        c += lc_batch[i];
        n += np_batch[i];
    }
    s_l[tid] = l; s_c[tid] = c; s_n[tid] = n;
    __syncthreads();
    for (int s = TPB / 2; s > 0; s >>= 1) {
        if (tid < s) {
            s_l[tid] += s_l[tid + s];
            s_c[tid] += s_c[tid + s];
            s_n[tid] += s_n[tid + s];
        }
        __syncthreads();
    }
    if (tid == 0) {
        float N = (float)s_n[0];
        out[0] = s_l[0] / N;
        out[1] = s_c[0] / N;
    }
}

extern "C" void kernel_launch(void* const* d_in, const int* in_sizes, int n_in,
                              void* d_out, int out_size, void* d_ws, size_t ws_size,
                              hipStream_t stream) {
    const float* loc = (const float*)d_in[0];
    const float* conf = (const float*)d_in[1];
    const float* priors = (const float*)d_in[2];
    const float* targets = (const float*)d_in[3];

    const int P = in_sizes[2] / 4;
    const int B = in_sizes[0] / (P * 4);
    const int C = in_sizes[1] / (in_sizes[0] / 4);  // conf / (B*P)
    const int O = in_sizes[3] / (B * 5);
    const size_t BP = (size_t)B * P;
    const int CB2 = (P + TPB - 1) / TPB;   // chunks per batch
    const int CB2W = CB2 * (TPB / 64);     // per-wave key entries

    // ws layout (8B-aligned first; everything fully written before read):
    ull* pkeys = (ull*)d_ws;                                 // B*O*CB2W u64
    float* mined = (float*)(pkeys + (size_t)B * O * CB2W);   // BP f32
    float* part_ll = mined + BP;                             // B*CB2 f32
    float* part_pc = part_ll + (size_t)B * CB2;              // B*CB2 f32
    int* part_np = (int*)(part_pc + (size_t)B * CB2);        // B*CB2 i32
    unsigned* chist = (unsigned*)(part_np + (size_t)B * CB2);  // B*CB2*128 u32
    float* ll_batch = (float*)(chist + (size_t)B * CB2 * 128); // B f32
    float* lc_batch = ll_batch + B;                          // B f32
    int* np_batch = (int*)(lc_batch + B);                    // B i32

    if (O == 8 && C == 21) {
        fused_kernel<8, 21><<<B * CB2, TPB, 0, stream>>>(
            loc, priors, targets, conf, P, O, C, CB2,
            mined, pkeys, part_ll, part_pc, part_np, chist);
        select_kernel<8, 21><<<B, TPBS, 0, stream>>>(
            mined, conf, loc, priors, targets, pkeys, part_ll, part_pc, part_np,
            chist, ll_batch, lc_batch, np_batch, P, O, C, CB2, 3);
    } else {
        fused_kernel<0, 0><<<B * CB2, TPB, 0, stream>>>(
            loc, priors, targets, conf, P, O, C, CB2,
            mined, pkeys, part_ll, part_pc, part_np, chist);
        select_kernel<0, 0><<<B, TPBS, 0, stream>>>(
            mined, conf, loc, priors, targets, pkeys, part_ll, part_pc, part_np,
            chist, ll_batch, lc_batch, np_batch, P, O, C, CB2, 3);
    }

    finalize_kernel<<<1, TPB, 0, stream>>>(ll_batch, np_batch, lc_batch, B,
                                           (float*)d_out);
}

// Round 4
// 116.779 us; speedup vs baseline: 1.0728x; 1.0094x over previous
//
#include <hip/hip_runtime.h>
#include <math.h>

#define TPB 256
#define SLOTS 4      // priors per fused thread (wave argmax covers 256 priors)
#define TPBS 1024    // select block size
#define NVREG 9      // register slots/thread in select (covers P <= 9216)

typedef unsigned long long ull;
typedef float pf4 __attribute__((ext_vector_type(4), aligned(4)));  // 4B-aligned float4

__device__ __forceinline__ float jac(float tx0, float ty0, float tx1, float ty1, float ta,
                                     float px0, float py0, float px1, float py1, float pa) {
    float ltx = fmaxf(tx0, px0), lty = fmaxf(ty0, py0);
    float rbx = fminf(tx1, px1), rby = fminf(ty1, py1);
    float w = fmaxf(rbx - ltx, 0.0f), h = fmaxf(rby - lty, 0.0f);
    float inter = w * h;
    return inter / (ta + pa - inter);
}

// R4: 4 priors/thread (slot s owns p = chunk*1024 + s*256 + tid).
//  - per-o argmax: one 6-level wave shuffle covers 256 priors (4x fewer
//    swizzles/prior); slot-ordered ballots keep the exact smallest-p tie
//    (all slot-s p's < all slot-(s+1) p's; within slot lowest lane wins).
//  - part sums keep the OLD 256-prior chunk granularity (one butterfly per
//    slot, same w=0..3 add order) -> every fp summation tree bit-identical.
//  - conf rows software-pipelined through rvA/rvB.
//  - per-chunk (1024-prior) top-byte histogram, u16-pair packed (counts<=1024).
template <int ON, int CN>
__global__ __launch_bounds__(TPB) void fused_kernel(
    const float* __restrict__ loc, const float* __restrict__ priors,
    const float* __restrict__ targets, const float* __restrict__ conf,
    int P, int O_rt, int C_rt, int CB2,
    float* __restrict__ mined, ull* __restrict__ pkeys,
    float* __restrict__ part_ll, float* __restrict__ part_pc,
    int* __restrict__ part_np, unsigned* __restrict__ chist) {
    constexpr int OMAX = (ON > 0) ? ON : 64;
    constexpr int CC = (CN > 0) ? CN : 32;
    constexpr int WPB = TPB / 64;  // 4 waves per block
    const int O = (ON > 0) ? ON : O_rt;
    const int C = (CN > 0) ? CN : C_rt;
    const int b = blockIdx.x / CB2;
    const int chunk = blockIdx.x % CB2;
    const int tid = threadIdx.x;
    const int base = chunk * (TPB * SLOTS);
    const int lane = tid & 63, wv = tid >> 6;
    const int CB2P = CB2 * SLOTS;  // per-wave key entries / old-chunk parts

    __shared__ float s_tx0[OMAX], s_ty0[OMAX], s_tx1[OMAX], s_ty1[OMAX];
    __shared__ float s_lab[OMAX], s_area[OMAX];
    __shared__ int s_h[256];
    __shared__ float s_wll[WPB][SLOTS], s_wpc[WPB][SLOTS];
    __shared__ int s_wnp[WPB][SLOTS];

    int p_[SLOTS];
    bool pv_[SLOTS];
#pragma unroll
    for (int s = 0; s < SLOTS; ++s) { p_[s] = base + s * TPB + tid; pv_[s] = p_[s] < P; }

    // prior corners (issued first; cx/cy/pw/ph reloaded L2-hot in phase B)
    float px0[SLOTS], py0[SLOTS], px1[SLOTS], py1[SLOTS], pa[SLOTS];
#pragma unroll
    for (int s = 0; s < SLOTS; ++s) {
        float4 pr = pv_[s] ? ((const float4*)priors)[p_[s]] : make_float4(0.f, 0.f, 1.f, 1.f);
        px0[s] = pr.x - pr.z * 0.5f; py0[s] = pr.y - pr.w * 0.5f;
        px1[s] = pr.x + pr.z * 0.5f; py1[s] = pr.y + pr.w * 0.5f;
        pa[s] = (px1[s] - px0[s]) * (py1[s] - py0[s]);
    }

    float rvA[CC], rvB[CC];
    auto loadrow = [&](float* rv, int p) {
        const float* row = conf + ((size_t)b * P + p) * C;
        if (CN > 0) {
#pragma unroll
            for (int q = 0; q < CN / 4; ++q) {
                pf4 v = *(const pf4*)(row + 4 * q);
#pragma unroll
                for (int e = 0; e < 4; ++e) rv[4 * q + e] = v[e];
            }
#pragma unroll
            for (int j = (CN / 4) * 4; j < CN; ++j) rv[j] = row[j];
        } else {
            for (int j = 0; j < C; ++j) rv[j] = row[j];
        }
    };
    if (pv_[0]) loadrow(rvA, p_[0]);  // slot0 row latency hides under phase A

    s_h[tid] = 0;  // TPB == 256: one bin each
    for (int o = tid; o < O; o += TPB) {
        const float* t = targets + ((size_t)b * O + o) * 5;
        float x0 = t[0], y0 = t[1], x1 = t[2], y1 = t[3];
        s_tx0[o] = x0; s_ty0[o] = y0; s_tx1[o] = x1; s_ty1[o] = y1;
        s_lab[o] = t[4];
        s_area[o] = (x1 - x0) * (y1 - y0);
    }
    __syncthreads();

    // ---- phase A: jac sweep. per-slot tentative best (strict >, earliest o)
    //      + per-o wave argmax over 4 slots (f32 butterfly + slot-ordered
    //      ballots -> exact smallest-p tie), lane0 key -> global ----
    float bto[SLOTS];
    int bti[SLOTS];
#pragma unroll
    for (int s = 0; s < SLOTS; ++s) { bto[s] = -1.0f; bti[s] = 0; }
    for (int o = 0; o < O; ++o) {
        float tx0 = s_tx0[o], ty0 = s_ty0[o], tx1 = s_tx1[o], ty1 = s_ty1[o], ta = s_area[o];
        float ov[SLOTS];
#pragma unroll
        for (int s = 0; s < SLOTS; ++s) {
            ov[s] = pv_[s] ? jac(tx0, ty0, tx1, ty1, ta,
                                 px0[s], py0[s], px1[s], py1[s], pa[s])
                           : -1.0f;
            if (ov[s] > bto[s]) { bto[s] = ov[s]; bti[s] = o; }
        }
        float mx = fmaxf(fmaxf(ov[0], ov[1]), fmaxf(ov[2], ov[3]));
#pragma unroll
        for (int d = 1; d < 64; d <<= 1)
            mx = fmaxf(mx, __shfl_xor(mx, d, 64));
        ull kk = 0ull;
        if (mx >= 0.0f) {  // wave-uniform
            ull m0 = __ballot(ov[0] == mx);
            int ss = 0;
            if (!m0) { m0 = __ballot(ov[1] == mx); ss = 1; }
            if (!m0) { m0 = __ballot(ov[2] == mx); ss = 2; }
            if (!m0) { m0 = __ballot(ov[3] == mx); ss = 3; }
            int src = __ffsll(m0) - 1;  // lowest lane in winning slot
            unsigned pw_ = (unsigned)(base + ss * TPB + (wv << 6) + src);
            kk = ((ull)__float_as_uint(mx) << 32) | (ull)(0xFFFFFFFFu - pw_);
        }
        if (lane == 0)
            pkeys[((size_t)b * O + o) * CB2P + chunk * WPB + wv] = kk;
    }

    // ---- phase B: per-slot conf LSE + tentative mined / sl1 / pos sums.
    // __expf/__logf identical (same intrinsic, same order) to select's fixup.
    float ll[SLOTS], pc[SLOTS];
    int np[SLOTS];
    auto doSlot = [&](int s, float* rv) {
        ll[s] = 0.0f; pc[s] = 0.0f; np[s] = 0;
        bool hv = false;
        int bn = 0;
        if (pv_[s]) {
            float m = rv[0];
#pragma unroll
            for (int j = 1; j < CC; ++j) { if (CN > 0 || j < C) m = fmaxf(m, rv[j]); }
            float sm = 0.0f;
#pragma unroll
            for (int j = 0; j < CC; ++j) { if (CN > 0 || j < C) sm += __expf(rv[j] - m); }
            float lse = m + __logf(sm);

            int c = (bto[s] < 0.5f) ? 0 : ((int)s_lab[bti[s]] + 1);
            float rowc = rv[0];
#pragma unroll
            for (int j = 1; j < CC; ++j) { if (CN > 0 || j < C) { if (c == j) rowc = rv[j]; } }
            float lc = lse - rowc;  // >= 0 always (sm >= 1)

            bool pos = c > 0;
            float mv = pos ? 0.0f : lc;
            mined[(size_t)b * P + p_[s]] = mv;
            bn = (int)(__float_as_uint(mv) >> 24);
            hv = true;
            if (pos) {
                pc[s] = lc;
                np[s] = 1;
                float4 pr = ((const float4*)priors)[p_[s]];  // L2-hot reload
                float cx = pr.x, cy = pr.y, pw = pr.z, ph = pr.w;
                float mx0 = s_tx0[bti[s]], my0 = s_ty0[bti[s]];
                float mx1 = s_tx1[bti[s]], my1 = s_ty1[bti[s]];
                float g0 = ((mx0 + mx1) * 0.5f - cx) / (0.1f * pw);
                float g1 = ((my0 + my1) * 0.5f - cy) / (0.1f * ph);
                float g2 = logf(fmaxf((mx1 - mx0) / pw, 1e-8f)) / 0.2f;
                float g3 = logf(fmaxf((my1 - my0) / ph, 1e-8f)) / 0.2f;
                float4 ld = ((const float4*)loc)[(size_t)b * P + p_[s]];
                float gt4[4] = {g0, g1, g2, g3};
                float lv[4] = {ld.x, ld.y, ld.z, ld.w};
#pragma unroll
                for (int q = 0; q < 4; ++q) {
                    float d = lv[q] - gt4[q];
                    float ad = fabsf(d);
                    ll[s] += (ad < 1.0f) ? 0.5f * d * d : (ad - 0.5f);
                }
            }
        }
        // top-byte histogram: wave-clustered LDS atomics (~few bins/wave)
        ull act = __ballot(hv);
        while (act) {
            int src = __ffsll(act) - 1;
            int b0 = __shfl(bn, src, 64);
            ull same = __ballot(hv && bn == b0) & act;
            if (lane == src) atomicAdd(&s_h[b0], (int)__popcll(same));
            act &= ~same;
        }
    };
    // software pipeline: load slot s+1's row while computing slot s
    if (pv_[1]) loadrow(rvB, p_[1]);
    doSlot(0, rvA);
    if (pv_[2]) loadrow(rvA, p_[2]);
    doSlot(1, rvB);
    if (pv_[3]) loadrow(rvB, p_[3]);
    doSlot(2, rvA);
    doSlot(3, rvB);

    // per-slot butterflies (OLD 256-prior chunk granularity -> bit-exact)
#pragma unroll
    for (int s = 0; s < SLOTS; ++s) {
        float l = ll[s], q = pc[s];
        int n = np[s];
#pragma unroll
        for (int d = 1; d < 64; d <<= 1) {
            l += __shfl_xor(l, d, 64);
            q += __shfl_xor(q, d, 64);
            n += __shfl_xor(n, d, 64);
        }
        if (lane == 0) { s_wll[wv][s] = l; s_wpc[wv][s] = q; s_wnp[wv][s] = n; }
    }
    __syncthreads();
    if (tid < SLOTS) {  // thread s sums slot s (same w=0..3 order as before)
        float L = 0.f, Pc = 0.f;
        int N = 0;
        for (int w = 0; w < WPB; ++w) { L += s_wll[w][tid]; Pc += s_wpc[w][tid]; N += s_wnp[w][tid]; }
        int pidx = b * CB2P + chunk * SLOTS + tid;
        part_ll[pidx] = L;
        part_pc[pidx] = Pc;
        part_np[pidx] = N;
    }
    if (tid < 128) {
        unsigned wd = (unsigned)s_h[2 * tid] | ((unsigned)s_h[2 * tid + 1] << 16);
        chist[((size_t)b * CB2 + chunk) * 128 + tid] = wd;
    }
}

// One 1024-thread block per batch; plain stores + tiny finalize dispatch
// (NO __threadfence — the R11 43-us constant stall).
//  Values register-resident: thread owns indices tid + j*1024, j<9.
//  Radix pass 0 precomputed from fused's per-chunk top-byte histograms
//  (+ forced-zero adjustment -> bit-identical counts); passes 1-3 single
//  256-int hist, plain atomics, direct s_hist[tid] scan.
//  sum(top-k) = sum_{>T} + (k-cnt_gt)*T — exact under ties.
template <int ON, int CN>
__global__ __launch_bounds__(TPBS) void select_kernel(
    const float* __restrict__ mined, const float* __restrict__ conf,
    const float* __restrict__ loc, const float* __restrict__ priors,
    const float* __restrict__ targets, const ull* __restrict__ pkeys,
    const float* __restrict__ part_ll, const float* __restrict__ part_pc,
    const int* __restrict__ part_np, const unsigned* __restrict__ chist,
    float* __restrict__ ll_batch, float* __restrict__ lc_batch,
    int* __restrict__ np_batch,
    int P, int O_rt, int C_rt, int CB2, int ratio) {
    constexpr int OMAX = (ON > 0) ? ON : 64;
    constexpr int NV = NVREG;
    const int O = (ON > 0) ? ON : O_rt;
    const int C = (CN > 0) ? CN : C_rt;
    const int b = blockIdx.x, tid = threadIdx.x;
    const int lane = tid & 63, wv = tid >> 6;
    constexpr int W = TPBS / 64;  // 16 waves
    const int CB2P = CB2 * SLOTS;  // part entries / per-wave key entries
    const float* v = mined + (size_t)b * P;
    const bool reg = (P <= NV * TPBS);

    __shared__ int s_hist[256];
    __shared__ float s_tx0[OMAX], s_ty0[OMAX], s_tx1[OMAX], s_ty1[OMAX];
    __shared__ float s_lab[OMAX], s_area[OMAX];
    __shared__ ull s_keys[OMAX];
    __shared__ int s_bp[OMAX];
    __shared__ float s_wf[W], s_wg[W];
    __shared__ int s_wi[W];
    __shared__ int s_wt[4];
    __shared__ unsigned s_bsel;
    __shared__ int s_krn;
    __shared__ float s_bc[2], s_fix[2];
    __shared__ int s_bn, s_fixn;

    // 0. issue the row loads FIRST — latency hides under the reductions below
    float val[NV];
#pragma unroll
    for (int j = 0; j < NV; ++j) {
        int i = tid + j * TPBS;
        val[j] = (reg && i < P) ? v[i] : 0.0f;
    }

    // 1. per-chunk tentative partial reduction
    float pll = 0.0f, ppc = 0.0f;
    int pnp = 0;
    for (int i = tid; i < CB2P; i += TPBS) {
        pll += part_ll[b * CB2P + i];
        ppc += part_pc[b * CB2P + i];
        pnp += part_np[b * CB2P + i];
    }
#pragma unroll
    for (int d = 1; d < 64; d <<= 1) {
        pll += __shfl_xor(pll, d, 64);
        ppc += __shfl_xor(ppc, d, 64);
        pnp += __shfl_xor(pnp, d, 64);
    }
    if (lane == 0) { s_wf[wv] = pll; s_wg[wv] = ppc; s_wi[wv] = pnp; }

    if (tid < O) {
        const float* t = targets + ((size_t)b * O + tid) * 5;
        float x0 = t[0], y0 = t[1], x1 = t[2], y1 = t[3];
        s_tx0[tid] = x0; s_ty0[tid] = y0; s_tx1[tid] = x1; s_ty1[tid] = y1;
        s_lab[tid] = t[4];
        s_area[tid] = (x1 - x0) * (y1 - y0);
        s_keys[tid] = 0ull;
    }
    __syncthreads();

    // 2. reduce per-wave keys (block-local LDS atomics, O*CB2P entries)
    for (int i = tid; i < O * CB2P; i += TPBS) {
        int o = i / CB2P, s = i % CB2P;
        atomicMax(&s_keys[o], pkeys[((size_t)b * O + o) * CB2P + s]);
    }
    __syncthreads();
    if (tid < O)
        s_bp[tid] = (int)(0xFFFFFFFFu - (unsigned)(s_keys[tid] & 0xFFFFFFFFull));
    __syncthreads();

    // zero forced priors in the register copy (forced -> positive -> mined 0)
    if (reg) {
#pragma unroll
        for (int j = 0; j < NV; ++j) {
            int i = tid + j * TPBS;
            bool z = false;
            for (int o = 0; o < O; ++o) z |= (s_bp[o] == i);
            if (z) val[j] = 0.0f;
        }
    }
    // one-time float->uint conversion for all radix passes
    unsigned uvv[NV];
#pragma unroll
    for (int j = 0; j < NV; ++j) uvv[j] = __float_as_uint(val[j]);

    // 2b. sum per-chunk top-byte histograms (bin = tid, u16 pair packed)
    if (tid < 256) {
        int h = 0;
        const unsigned* cb = chist + (size_t)b * CB2 * 128 + (tid >> 1);
        const int sh = (tid & 1) * 16;
        for (int c = 0; c < CB2; ++c) h += (int)((cb[c * 128] >> sh) & 0xFFFFu);
        s_hist[tid] = h;
    }

    // 3. FIXUP deltas (wave-0 lanes; proven bit-exact in R9/R11).
    float dll = 0.0f, dpc = 0.0f;
    int dnp = 0;
    int adj_bin = -1;  // hist adjustment: tentative value's top byte
    if (tid < O) {
        const int o = tid;
        const int p = s_bp[o];
        bool owner = true;
        for (int o2 = o + 1; o2 < O; ++o2)
            if (s_bp[o2] == p) owner = false;  // largest o owns (last-wins scatter)
        if (owner) {
            adj_bin = (int)(__float_as_uint(v[p]) >> 24);
            float4 pr = ((const float4*)priors)[p];
            float cx = pr.x, cy = pr.y, pw = pr.z, ph = pr.w;
            float px0 = cx - pw * 0.5f, py0 = cy - ph * 0.5f;
            float px1 = cx + pw * 0.5f, py1 = cy + ph * 0.5f;
            float pa = (px1 - px0) * (py1 - py0);
            float bto = -1.0f;
            int bti = 0;
            for (int o2 = 0; o2 < O; ++o2) {
                float ov = jac(s_tx0[o2], s_ty0[o2], s_tx1[o2], s_ty1[o2], s_area[o2],
                               px0, py0, px1, py1, pa);
                if (ov > bto) { bto = ov; bti = o2; }
            }
            int c_t = (bto < 0.5f) ? 0 : ((int)s_lab[bti] + 1);
            const float* row = conf + ((size_t)b * P + p) * C;
            float m = row[0];
            for (int j = 1; j < C; ++j) m = fmaxf(m, row[j]);
            float s = 0.0f;
            for (int j = 0; j < C; ++j) s += __expf(row[j] - m);
            float lse = m + __logf(s);
            int c_n = (int)s_lab[o] + 1;
            float lc_n = lse - row[c_n];
            bool pos_t = c_t > 0;
            float lc_t = lse - row[c_t];
            dpc = lc_n - (pos_t ? lc_t : 0.0f);
            dnp = 1 - (pos_t ? 1 : 0);
            float4 ld = ((const float4*)loc)[(size_t)b * P + p];
            float lv[4] = {ld.x, ld.y, ld.z, ld.w};
            float sl_new = 0.0f, sl_old = 0.0f;
            {
                float mx0 = s_tx0[o], my0 = s_ty0[o], mx1 = s_tx1[o], my1 = s_ty1[o];
                float g[4] = {((mx0 + mx1) * 0.5f - cx) / (0.1f * pw),
                              ((my0 + my1) * 0.5f - cy) / (0.1f * ph),
                              logf(fmaxf((mx1 - mx0) / pw, 1e-8f)) / 0.2f,
                              logf(fmaxf((my1 - my0) / ph, 1e-8f)) / 0.2f};
                for (int q = 0; q < 4; ++q) {
                    float d = lv[q] - g[q];
                    float ad = fabsf(d);
                    sl_new += (ad < 1.0f) ? 0.5f * d * d : (ad - 0.5f);
                }
            }
            if (pos_t) {
                float mx0 = s_tx0[bti], my0 = s_ty0[bti], mx1 = s_tx1[bti], my1 = s_ty1[bti];
                float g[4] = {((mx0 + mx1) * 0.5f - cx) / (0.1f * pw),
                              ((my0 + my1) * 0.5f - cy) / (0.1f * ph),
                              logf(fmaxf((mx1 - mx0) / pw, 1e-8f)) / 0.2f,
                              logf(fmaxf((my1 - my0) / ph, 1e-8f)) / 0.2f};
                for (int q = 0; q < 4; ++q) {
                    float d = lv[q] - g[q];
                    float ad = fabsf(d);
                    sl_old += (ad < 1.0f) ? 0.5f * d * d : (ad - 0.5f);
                }
            }
            dll = sl_new - sl_old;
        }
    }
    if (wv == 0) {
#pragma unroll
        for (int d = 1; d < 64; d <<= 1) {
            dll += __shfl_xor(dll, d, 64);
            dpc += __shfl_xor(dpc, d, 64);
            dnp += __shfl_xor(dnp, d, 64);
        }
        if (lane == 0) { s_fix[0] = dll; s_fix[1] = dpc; s_fixn = dnp; }
    }
    __syncthreads();
    // forced-zero hist adjustment (owners; matches zeroed registers exactly)
    if (adj_bin > 0) {  // adj_bin==0: -1/+1 on bin 0 cancels, skip
        atomicAdd(&s_hist[adj_bin], -1);
        atomicAdd(&s_hist[0], 1);
    }
    if (tid == 0) {
        float L = 0.f, Pc = 0.f;
        int N = 0;
        for (int w = 0; w < W; ++w) { L += s_wf[w]; Pc += s_wg[w]; N += s_wi[w]; }
        s_bc[0] = L + s_fix[0]; s_bc[1] = Pc + s_fix[1]; s_bn = N + s_fixn;
    }
    __syncthreads();
    const float ll_sum = s_bc[0];
    const float sum_pos = s_bc[1];
    const int npos = s_bn;

    const int k = min(ratio * npos, P - npos);
    if (tid == 0) {
        ll_batch[b] = ll_sum;
        np_batch[b] = npos;
    }
    if (k <= 0) {
        if (tid == 0) lc_batch[b] = sum_pos;
        return;
    }

    // 4. radix-select: pass 0 scan uses the precomputed+adjusted hist;
    //    passes 1-3 build a fresh single hist from the register copy.
    unsigned prefix = 0u;
    int kr = k;
    for (int pass = 0; pass < 4; ++pass) {
        const int shift = 24 - 8 * pass;
        if (pass > 0) {
            const unsigned mask = 0xFFFFFFFFu << (32 - 8 * pass);
            if (tid < 256) s_hist[tid] = 0;
            __syncthreads();
            if (reg) {
#pragma unroll
                for (int j = 0; j < NV; ++j) {
                    int i = tid + j * TPBS;
                    unsigned u = uvv[j];
                    if (i < P && (u & mask) == prefix)
                        atomicAdd(&s_hist[(u >> shift) & 0xFF], 1);
                }
            } else {
                for (int i = tid; i < P; i += TPBS) {
                    float x = v[i];
                    for (int o = 0; o < O; ++o)
                        if (i == s_bp[o]) x = 0.0f;
                    unsigned u = __float_as_uint(x);
                    if ((u & mask) == prefix)
                        atomicAdd(&s_hist[(u >> shift) & 0xFF], 1);
                }
            }
            __syncthreads();
        }
        int sge = 0, h = 0;
        if (tid < 256) {
            h = s_hist[tid];
            int val_ = h;
#pragma unroll
            for (int d = 1; d < 64; d <<= 1) {
                int t = __shfl_down(val_, d, 64);
                if (lane + d < 64) val_ += t;
            }
            if (lane == 0) s_wt[tid >> 6] = val_;
            sge = val_;
        }
        __syncthreads();
        if (tid < 256) {
            for (int w = (tid >> 6) + 1; w < 4; ++w) sge += s_wt[w];
            int sgt = sge - h;
            if (sge >= kr && sgt < kr) {  // exactly one tid satisfies
                s_bsel = (unsigned)tid;
                s_krn = kr - sgt;
            }
        }
        __syncthreads();
        prefix |= s_bsel << shift;
        kr = s_krn;
        // next pass's clear happens after a barrier; s_bsel/s_krn rewritten
        // only after two more barriers — no hazard
    }
    const float T = __uint_as_float(prefix);  // exact k-th largest value
    float lsum = 0.0f;
    int lcnt = 0;
    if (reg) {
#pragma unroll
        for (int j = 0; j < NV; ++j) {
            int i = tid + j * TPBS;
            if (i < P && val[j] > T) { lsum += val[j]; ++lcnt; }
        }
    } else {
        for (int i = tid; i < P; i += TPBS) {
            float x = v[i];
            for (int o = 0; o < O; ++o)
                if (i == s_bp[o]) x = 0.0f;
            if (x > T) { lsum += x; ++lcnt; }
        }
    }
#pragma unroll
    for (int d = 1; d < 64; d <<= 1) {
        lsum += __shfl_xor(lsum, d, 64);
        lcnt += __shfl_xor(lcnt, d, 64);
    }
    if (lane == 0) { s_wf[wv] = lsum; s_wi[wv] = lcnt; }
    __syncthreads();
    if (tid == 0) {
        float S = 0.f;
        int Cn = 0;
        for (int w = 0; w < W; ++w) { S += s_wf[w]; Cn += s_wi[w]; }
        lc_batch[b] = sum_pos + S + (float)(k - Cn) * T;
    }
}

__global__ __launch_bounds__(TPB) void finalize_kernel(
    const float* __restrict__ ll_batch, const int* __restrict__ np_batch,
    const float* __restrict__ lc_batch, int B, float* __restrict__ out) {
    const int tid = threadIdx.x;
    __shared__ float s_l[TPB], s_c[TPB];
    __shared__ int s_n[TPB];
    float l = 0.0f, c = 0.0f;
    int n = 0;
    for (int i = tid; i < B; i += TPB) {
        l += ll_batch[i];
        c += lc_batch[i];
        n += np_batch[i];
    }
    s_l[tid] = l; s_c[tid] = c; s_n[tid] = n;
    __syncthreads();
    for (int s = TPB / 2; s > 0; s >>= 1) {
        if (tid < s) {
            s_l[tid] += s_l[tid + s];
            s_c[tid] += s_c[tid + s];
            s_n[tid] += s_n[tid + s];
        }
        __syncthreads();
    }
    if (tid == 0) {
        float N = (float)s_n[0];
        out[0] = s_l[0] / N;
        out[1] = s_c[0] / N;
    }
}

extern "C" void kernel_launch(void* const* d_in, const int* in_sizes, int n_in,
                              void* d_out, int out_size, void* d_ws, size_t ws_size,
                              hipStream_t stream) {
    const float* loc = (const float*)d_in[0];
    const float* conf = (const float*)d_in[1];
    const float* priors = (const float*)d_in[2];
    const float* targets = (const float*)d_in[3];

    const int P = in_sizes[2] / 4;
    const int B = in_sizes[0] / (P * 4);
    const int C = in_sizes[1] / (in_sizes[0] / 4);  // conf / (B*P)
    const int O = in_sizes[3] / (B * 5);
    const size_t BP = (size_t)B * P;
    const int CB2 = (P + TPB * SLOTS - 1) / (TPB * SLOTS);  // 1024-prior chunks
    const int CB2P = CB2 * SLOTS;                            // 256-prior parts/keys

    // ws layout (8B-aligned first; everything fully written before read):
    ull* pkeys = (ull*)d_ws;                                  // B*O*CB2P u64
    float* mined = (float*)(pkeys + (size_t)B * O * CB2P);    // BP f32
    float* part_ll = mined + BP;                              // B*CB2P f32
    float* part_pc = part_ll + (size_t)B * CB2P;              // B*CB2P f32
    int* part_np = (int*)(part_pc + (size_t)B * CB2P);        // B*CB2P i32
    unsigned* chist = (unsigned*)(part_np + (size_t)B * CB2P);   // B*CB2*128 u32
    float* ll_batch = (float*)(chist + (size_t)B * CB2 * 128);   // B f32
    float* lc_batch = ll_batch + B;                           // B f32
    int* np_batch = (int*)(lc_batch + B);                     // B i32

    if (O == 8 && C == 21) {
        fused_kernel<8, 21><<<B * CB2, TPB, 0, stream>>>(
            loc, priors, targets, conf, P, O, C, CB2,
            mined, pkeys, part_ll, part_pc, part_np, chist);
        select_kernel<8, 21><<<B, TPBS, 0, stream>>>(
            mined, conf, loc, priors, targets, pkeys, part_ll, part_pc, part_np,
            chist, ll_batch, lc_batch, np_batch, P, O, C, CB2, 3);
    } else {
        fused_kernel<0, 0><<<B * CB2, TPB, 0, stream>>>(
            loc, priors, targets, conf, P, O, C, CB2,
            mined, pkeys, part_ll, part_pc, part_np, chist);
        select_kernel<0, 0><<<B, TPBS, 0, stream>>>(
            mined, conf, loc, priors, targets, pkeys, part_ll, part_pc, part_np,
            chist, ll_batch, lc_batch, np_batch, P, O, C, CB2, 3);
    }

    finalize_kernel<<<1, TPB, 0, stream>>>(ll_batch, np_batch, lc_batch, B,
                                           (float*)d_out);
}